// Round 17
// baseline (2279.987 us; speedup 1.0000x reference)
//
#include <hip/hip_runtime.h>
#include <hip/hip_bf16.h>

// GumbelSoftmaxTokenizer: B=8, P=16384, FEAT=6, TOK=768, MT=128, K=16, IH=256
// All inputs float32; output buffer float32 (tokens, cents, masks concat).
#define NPT   131072      // B*P
#define BATCH 8
#define PPE   16384
#define MT    128
#define KNN   16
#define TOKD  768

typedef short bf16x8 __attribute__((ext_vector_type(8)));
typedef float f32x4  __attribute__((ext_vector_type(4)));

#define GL16(g, l) __builtin_amdgcn_global_load_lds(                         \
    (const __attribute__((address_space(1))) void*)(g),                      \
    (__attribute__((address_space(3))) void*)(l), 16, 0, 0)

#define HSTR 264   // per-wave hist stride (bank-decorrelated)

__device__ __forceinline__ unsigned pack_hi(unsigned u0, unsigned u1) {
    return (u0 >> 16) | (u1 & 0xFFFF0000u);
}
__device__ __forceinline__ void split1(float x, short& h, short& l) {
    const unsigned u = __float_as_uint(x);
    h = (short)(u >> 16);
    const float r = x - __uint_as_float(u & 0xFFFF0000u);
    l = (short)(__float_as_uint(r) >> 16);
}
// lane-major d16 slot <-> point id (p = tid + i*256, slot = tid*64 + i)
__device__ __forceinline__ int slot_of(int p)  { return ((p & 255) << 6) | (p >> 8); }
__device__ __forceinline__ int point_of(int s) { return (s >> 6) | ((s & 63) << 8); }

// ---------------------------------------------------------------------------
// prep: c4f[i] = coords[i,1:5] packed float4
// ---------------------------------------------------------------------------
__global__ __launch_bounds__(256) void prep_kernel(const float* __restrict__ coords,
                                                   float4* __restrict__ c4f)
{
    const int i = blockIdx.x * 256 + threadIdx.x;
    if (i < NPT) {
        const long b = (long)i * 5;
        c4f[i] = make_float4(coords[b + 1], coords[b + 2], coords[b + 3], coords[b + 4]);
    }
}

// ---------------------------------------------------------------------------
// Weight pre-convert: W(KxN f32) -> hi/lo [N][Kpad] bf16 (transposed, padded)
// ---------------------------------------------------------------------------
__global__ __launch_bounds__(256) void wsplit_kernel(const float* __restrict__ W,
                                                     int K, int N, int Kpad,
                                                     short* __restrict__ hi,
                                                     short* __restrict__ lo)
{
    const int n = blockIdx.x;
    for (int k = threadIdx.x; k < Kpad; k += 256) {
        short h = 0, l = 0;
        if (k < K) split1(W[(long)k * N + n], h, l);
        hi[(long)n * Kpad + k] = h;
        lo[(long)n * Kpad + k] = l;
    }
}

// ---------------------------------------------------------------------------
// W45 fusion: W45ext[N=256][Kpad=800] planes + bias45 (exact: L4 has no relu)
// ---------------------------------------------------------------------------
__global__ __launch_bounds__(256) void w45_kernel(const float* __restrict__ w4,
                                                  const float* __restrict__ iw1,
                                                  const float* __restrict__ b4,
                                                  const float* __restrict__ ib1,
                                                  short* __restrict__ hi,
                                                  short* __restrict__ lo,
                                                  float* __restrict__ bias45)
{
    const int n = blockIdx.x, tid = threadIdx.x;
    __shared__ float col[772];
    for (int j = tid; j < 772; j += 256) col[j] = iw1[(long)j * 256 + n];
    __syncthreads();
    for (int k = tid; k < 800; k += 256) {
        float v = 0.f;
        if (k < 768) {
            const float* wr = &w4[(long)k * 768];
            for (int j = 0; j < 768; ++j) v += wr[j] * col[j];
        } else if (k < 772) {
            v = col[k];
        }
        short h, l; split1(v, h, l);
        hi[(long)n * 800 + k] = h;
        lo[(long)n * 800 + k] = l;
    }
    float s = 0.f;
    for (int j = tid; j < 768; j += 256) s += b4[j] * col[j];
#pragma unroll
    for (int off = 32; off; off >>= 1) s += __shfl_down(s, off);
    __shared__ float part[4];
    if ((tid & 63) == 0) part[tid >> 6] = s;
    __syncthreads();
    if (tid == 0) bias45[n] = part[0] + part[1] + part[2] + part[3] + ib1[n];
}

// ---------------------------------------------------------------------------
// L1 multi-row: 64 rows/block
// ---------------------------------------------------------------------------
__global__ __launch_bounds__(256) void l1_kernel(const float* __restrict__ f,
                                                 const float* __restrict__ w1,
                                                 const float* __restrict__ b1,
                                                 short* __restrict__ hp,
                                                 short* __restrict__ lp,
                                                 int base,
                                                 const int* __restrict__ gather)
{
    const int r0 = blockIdx.x << 6, tid = threadIdx.x;
    float wc[6];
#pragma unroll
    for (int k = 0; k < 6; ++k) wc[k] = w1[k * 256 + tid];
    const float bb = b1[tid];
    for (int i = 0; i < 64; ++i) {
        const int r = r0 + i;
        int row = gather ? gather[r] : (base + r);
        row = (row < 0) ? 0 : ((row >= NPT) ? (NPT - 1) : row);
        float acc = bb;
#pragma unroll
        for (int k = 0; k < 6; ++k) acc += f[(long)row * 6 + k] * wc[k];
        acc = fmaxf(acc, 0.f);
        short h, l; split1(acc, h, l);
        hp[(long)r * 256 + tid] = h;
        lp[(long)r * 256 + tid] = l;
    }
}

// ---------------------------------------------------------------------------
// a2fill: plane cols 768..799 (stride 800)
// ---------------------------------------------------------------------------
__global__ __launch_bounds__(256) void a2fill_kernel(const float* __restrict__ coords,
                                                     int base, int ch,
                                                     short* __restrict__ hp,
                                                     short* __restrict__ lp)
{
    const int idx = blockIdx.x * 256 + threadIdx.x;
    if (idx >= ch * 32) return;
    const int r = idx >> 5, c = idx & 31;
    short h = 0, l = 0;
    if (c < 4) split1(coords[(long)(base + r) * 5 + 1 + c], h, l);
    hp[(long)r * 800 + 768 + c] = h;
    lp[(long)r * 800 + 768 + c] = l;
}

// ---------------------------------------------------------------------------
// gather_h3: G[i][0:768] = H3[knn[off+i]][0:768]
// ---------------------------------------------------------------------------
__global__ __launch_bounds__(256) void gather_h3_kernel(const short* __restrict__ H3,
                                                        const int* __restrict__ knn_idx,
                                                        int off,
                                                        short* __restrict__ G)
{
    const int i = blockIdx.x;
    const int row = knn_idx[off + i];
    const int4* src = (const int4*)(H3 + (long)row * 768);
    int4* dst = (int4*)(G + (long)i * 768);
    if (threadIdx.x < 96) dst[threadIdx.x] = src[threadIdx.x];
}

// ---------------------------------------------------------------------------
// Split-bf16 MFMA GEMM. New: Cpool mode — fused 16-row-group max-pool output
// (pooled[row0/16 + wave*2+mt][col] = max over the group's 16 rows).
// ---------------------------------------------------------------------------
__global__ __launch_bounds__(256) void gemm_mf(
    const short* __restrict__ Aph, const short* __restrict__ Apl,
    const float* __restrict__ Afp, int Kpad,
    const short* __restrict__ Wth, const short* __restrict__ Wtl,
    const float* __restrict__ bias,
    short* __restrict__ Cph, short* __restrict__ Cpl, int KpadOut,
    float* __restrict__ Cf, short* __restrict__ Cp768,
    float* __restrict__ Cpool,
    int N, int relu)
{
    __shared__ short Ah[128 * 32];
    __shared__ short Al[128 * 32];
    __shared__ short Bh[128 * 32];
    __shared__ short Bl[128 * 32];
    const int tid = threadIdx.x;
    int rowb, colb;
    {
        const int ncol = gridDim.x, nrow = gridDim.y;
        if ((nrow & 7) == 0) {
            const int id  = blockIdx.y * ncol + blockIdx.x;
            const int sgs = ncol << 3;
            const int sg = id / sgs, wi = id % sgs;
            rowb = (sg << 3) + (wi & 7);
            colb = wi >> 3;
        } else { rowb = blockIdx.y; colb = blockIdx.x; }
    }
    const int row0 = rowb << 7, col0 = colb << 7;
    const int wave = tid >> 6, lane = tid & 63;
    const int q = lane >> 4, l16 = lane & 15;
    const int l2 = lane >> 2;
    const int ks = (lane & 3) << 3;

    f32x4 acc[2][8];
#pragma unroll
    for (int mt = 0; mt < 2; ++mt)
#pragma unroll
        for (int nt = 0; nt < 8; ++nt)
            acc[mt][nt] = (f32x4){0.f, 0.f, 0.f, 0.f};

    const int nk = Kpad >> 5;
    for (int t = 0; t < nk; ++t) {
        const int k0 = t << 5;
#pragma unroll
        for (int i = 0; i < 2; ++i) {
            const int mb = (wave << 5) + (i << 4);
            const long gb = (long)(col0 + mb + l2) * Kpad + k0 + ks;
            GL16(&Wth[gb], &Bh[mb * 32]);
            GL16(&Wtl[gb], &Bl[mb * 32]);
        }
        if (Aph) {
#pragma unroll
            for (int i = 0; i < 2; ++i) {
                const int mb = (wave << 5) + (i << 4);
                const long ga = (long)(row0 + mb + l2) * Kpad + k0 + ks;
                GL16(&Aph[ga], &Ah[mb * 32]);
                if (Apl) GL16(&Apl[ga], &Al[mb * 32]);
            }
        } else {
#pragma unroll
            for (int s = 0; s < 4; ++s) {
                const int l  = (s << 8) + tid;
                const int m  = l >> 3;
                const int k4 = (l & 7) << 2;
                const float4 v = *(const float4*)&Afp[(long)(row0 + m) * Kpad + k0 + k4];
                const unsigned u0 = __float_as_uint(v.x), u1 = __float_as_uint(v.y);
                const unsigned u2 = __float_as_uint(v.z), u3 = __float_as_uint(v.w);
                const unsigned r0 = __float_as_uint(v.x - __uint_as_float(u0 & 0xFFFF0000u));
                const unsigned r1 = __float_as_uint(v.y - __uint_as_float(u1 & 0xFFFF0000u));
                const unsigned r2 = __float_as_uint(v.z - __uint_as_float(u2 & 0xFFFF0000u));
                const unsigned r3 = __float_as_uint(v.w - __uint_as_float(u3 & 0xFFFF0000u));
                *(int2*)&Ah[m * 32 + k4] = make_int2((int)pack_hi(u0, u1), (int)pack_hi(u2, u3));
                *(int2*)&Al[m * 32 + k4] = make_int2((int)pack_hi(r0, r1), (int)pack_hi(r2, r3));
            }
        }
        __syncthreads();
        const bool useAl = (Apl != nullptr) || (Aph == nullptr);
        bf16x8 ah[2], al[2];
#pragma unroll
        for (int mt = 0; mt < 2; ++mt) {
            const int mrow = (wave << 5) + (mt << 4) + l16;
            ah[mt] = *(const bf16x8*)&Ah[mrow * 32 + (q << 3)];
            if (useAl) al[mt] = *(const bf16x8*)&Al[mrow * 32 + (q << 3)];
        }
#pragma unroll
        for (int nt = 0; nt < 8; ++nt) {
            const int ncol2 = (nt << 4) + l16;
            const bf16x8 bh = *(const bf16x8*)&Bh[ncol2 * 32 + (q << 3)];
            const bf16x8 bl = *(const bf16x8*)&Bl[ncol2 * 32 + (q << 3)];
#pragma unroll
            for (int mt = 0; mt < 2; ++mt) {
                acc[mt][nt] = __builtin_amdgcn_mfma_f32_16x16x32_bf16(ah[mt], bh, acc[mt][nt], 0, 0, 0);
                acc[mt][nt] = __builtin_amdgcn_mfma_f32_16x16x32_bf16(ah[mt], bl, acc[mt][nt], 0, 0, 0);
                if (useAl)
                    acc[mt][nt] = __builtin_amdgcn_mfma_f32_16x16x32_bf16(al[mt], bh, acc[mt][nt], 0, 0, 0);
            }
        }
        __syncthreads();
    }
    if (Cpool) {
        // fused max over each 16-row group (= one (wave,mt) fragment)
#pragma unroll
        for (int mt = 0; mt < 2; ++mt)
#pragma unroll
            for (int nt = 0; nt < 8; ++nt) {
                const int col = col0 + (nt << 4) + l16;
                float m = fmaxf(fmaxf(acc[mt][nt][0], acc[mt][nt][1]),
                                fmaxf(acc[mt][nt][2], acc[mt][nt][3]));
                m = fmaxf(m, __shfl_xor(m, 16));
                m = fmaxf(m, __shfl_xor(m, 32));
                m += bias[col];
                if (relu) m = fmaxf(m, 0.f);
                if (q == 0)
                    Cpool[(long)((row0 >> 4) + (wave << 1) + mt) * 768 + col] = m;
            }
        return;
    }
#pragma unroll
    for (int mt = 0; mt < 2; ++mt)
#pragma unroll
        for (int nt = 0; nt < 8; ++nt) {
            const int col = col0 + (nt << 4) + l16;
            const float bs = bias[col];
#pragma unroll
            for (int rg = 0; rg < 4; ++rg) {
                const int row = row0 + (wave << 5) + (mt << 4) + (q << 2) + rg;
                float v = acc[mt][nt][rg] + bs;
                if (relu) v = fmaxf(v, 0.f);
                if (Cf) Cf[(long)row * N + col] = v;
                if (Cph || Cp768) {
                    short h, l; split1(v, h, l);
                    if (Cph) {
                        Cph[(long)row * KpadOut + col] = h;
                        Cpl[(long)row * KpadOut + col] = l;
                    }
                    if (Cp768) Cp768[(long)row * 768 + col] = h;
                }
            }
        }
}

// ---------------------------------------------------------------------------
// LayerNorm multi-row: wave per row x 8 rows
// ---------------------------------------------------------------------------
__global__ __launch_bounds__(256) void ln_kernel(const float* __restrict__ z,
                                                 const float* __restrict__ g,
                                                 const float* __restrict__ b,
                                                 short* __restrict__ hp,
                                                 short* __restrict__ lp)
{
    const int tid = threadIdx.x, wave = tid >> 6, lane = tid & 63;
    float gv[4], bv[4];
#pragma unroll
    for (int j = 0; j < 4; ++j) { gv[j] = g[lane * 4 + j]; bv[j] = b[lane * 4 + j]; }
    for (int i = 0; i < 8; ++i) {
        const int r = (blockIdx.x << 5) + (wave << 3) + i;
        const float4 x = *(const float4*)&z[(long)r * 256 + lane * 4];
        float s = x.x + x.y + x.z + x.w;
#pragma unroll
        for (int off = 32; off; off >>= 1) s += __shfl_down(s, off);
        const float mu = __shfl(s, 0) * (1.f / 256.f);
        const float d0 = x.x - mu, d1 = x.y - mu, d2 = x.z - mu, d3 = x.w - mu;
        float s2 = d0 * d0 + d1 * d1 + d2 * d2 + d3 * d3;
#pragma unroll
        for (int off = 32; off; off >>= 1) s2 += __shfl_down(s2, off);
        const float den = sqrtf(__shfl(s2, 0) * (1.f / 256.f) + 1e-5f);
        const float v[4] = { d0 / den * gv[0] + bv[0], d1 / den * gv[1] + bv[1],
                             d2 / den * gv[2] + bv[2], d3 / den * gv[3] + bv[3] };
#pragma unroll
        for (int j = 0; j < 4; ++j) {
            short h, l; split1(v[j], h, l);
            hp[(long)r * 256 + lane * 4 + j] = h;
            lp[(long)r * 256 + lane * 4 + j] = l;
        }
    }
}

// ---------------------------------------------------------------------------
// imp multi-row: wave per row x 8
// ---------------------------------------------------------------------------
__global__ __launch_bounds__(256) void imp_kernel(const float* __restrict__ z2,
                                                  const float* __restrict__ iw3,
                                                  const float* __restrict__ ib3,
                                                  const float* __restrict__ noise,
                                                  const float* __restrict__ lt,
                                                  float* __restrict__ pert,
                                                  int base)
{
    const int tid = threadIdx.x, wave = tid >> 6, lane = tid & 63;
    float wv[4];
#pragma unroll
    for (int j = 0; j < 4; ++j) wv[j] = iw3[lane * 4 + j];
    const float temp = fmaxf(expf(lt[0]), 0.1f);
    const float b3v = ib3[0];
    for (int i = 0; i < 8; ++i) {
        const int r = (blockIdx.x << 5) + (wave << 3) + i;
        const float4 x = *(const float4*)&z2[(long)r * 256 + lane * 4];
        float s = x.x * wv[0] + x.y * wv[1] + x.z * wv[2] + x.w * wv[3];
#pragma unroll
        for (int off = 32; off; off >>= 1) s += __shfl_down(s, off);
        if (lane == 0)
            pert[base + r] = (s + b3v + noise[base + r]) / temp;
    }
}

// ---------------------------------------------------------------------------
// top-128 per event: 2-level cached radix; lane-major d16 slots (int4 LDS
// sweeps) + per-wave x4 bank-decorrelated histograms.
// ---------------------------------------------------------------------------
__device__ __forceinline__ unsigned fmap(float f) {
    unsigned x = __float_as_uint(f);
    return (x & 0x80000000u) ? ~x : (x | 0x80000000u);
}

__global__ __launch_bounds__(256) void topk_kernel(const float* __restrict__ pert,
                                                   const float4* __restrict__ c4f,
                                                   float* __restrict__ centf)
{
    const int e = blockIdx.x, tid = threadIdx.x;
    const int base = e * PPE;
    const int wave = tid >> 6;
    __shared__ unsigned short d16[PPE];          // 32 KB, lane-major slots
    __shared__ unsigned histw[4 * HSTR];
    __shared__ int sh_need; __shared__ unsigned sh_b;
    for (int w = 0; w < 4; ++w) histw[w * HSTR + tid] = 0;
    __syncthreads();
    {
        unsigned pk[4];
        for (int i = 0; i < 64; ++i) {
            const int p = tid + (i << 8);
            const unsigned u = fmap(pert[base + p]);
            const unsigned hw = u >> 16;
            if (i & 1) pk[(i & 7) >> 1] |= hw << 16; else pk[(i & 7) >> 1] = hw;
            atomicAdd(&histw[wave * HSTR + (u >> 24)], 1u);
            if ((i & 7) == 7)
                *(int4*)&d16[(tid << 6) + (i & ~7)] =
                    make_int4((int)pk[0], (int)pk[1], (int)pk[2], (int)pk[3]);
        }
    }
    __syncthreads();
    if (tid == 0) {
        int cum = 0, b = 255;
        for (; b > 0; --b) {
            cum += (int)(histw[b] + histw[HSTR + b] + histw[2 * HSTR + b] + histw[3 * HSTR + b]);
            if (cum >= MT) break;
        }
        if (cum < MT) { cum += (int)(histw[0] + histw[HSTR] + histw[2 * HSTR] + histw[3 * HSTR]); b = 0; }
        sh_need = MT - (cum - (int)(histw[b] + histw[HSTR + b] + histw[2 * HSTR + b] + histw[3 * HSTR + b]));
        sh_b = (unsigned)b;
    }
    __syncthreads();
    int need = sh_need;
    const unsigned b1v = sh_b;
    __syncthreads();
    for (int w = 0; w < 4; ++w) histw[w * HSTR + tid] = 0;
    __syncthreads();
    for (int v8 = 0; v8 < 8; ++v8) {
        const int4 v = *(const int4*)&d16[(tid << 6) + (v8 << 3)];
        const unsigned uu[4] = {(unsigned)v.x, (unsigned)v.y, (unsigned)v.z, (unsigned)v.w};
#pragma unroll
        for (int j = 0; j < 4; ++j) {
            const unsigned h0 = uu[j] & 0xFFFFu, h1 = uu[j] >> 16;
            if ((h0 >> 8) == b1v) atomicAdd(&histw[wave * HSTR + (h0 & 255u)], 1u);
            if ((h1 >> 8) == b1v) atomicAdd(&histw[wave * HSTR + (h1 & 255u)], 1u);
        }
    }
    __syncthreads();
    if (tid == 0) {
        int cum = 0, b = 255;
        for (; b > 0; --b) {
            cum += (int)(histw[b] + histw[HSTR + b] + histw[2 * HSTR + b] + histw[3 * HSTR + b]);
            if (cum >= need) break;
        }
        if (cum < need) { cum += (int)(histw[0] + histw[HSTR] + histw[2 * HSTR] + histw[3 * HSTR]); b = 0; }
        sh_need = need - (cum - (int)(histw[b] + histw[HSTR + b] + histw[2 * HSTR + b] + histw[3 * HSTR + b]));
        sh_b = (unsigned)b;
    }
    __syncthreads();
    need = sh_need;
    const unsigned prefix16 = (b1v << 8) | sh_b;
    __shared__ int gt_i[MT];
    __shared__ unsigned gt_u[MT];
    __shared__ int eqbuf[256];
    __shared__ int cgt, ceq;
    if (tid == 0) { cgt = 0; ceq = 0; }
    __syncthreads();
    for (int v8 = 0; v8 < 8; ++v8) {
        const int4 v = *(const int4*)&d16[(tid << 6) + (v8 << 3)];
        const unsigned uu[4] = {(unsigned)v.x, (unsigned)v.y, (unsigned)v.z, (unsigned)v.w};
#pragma unroll
        for (int j = 0; j < 4; ++j) {
#pragma unroll
            for (int hh = 0; hh < 2; ++hh) {
                const unsigned h = hh ? (uu[j] >> 16) : (uu[j] & 0xFFFFu);
                const int s = (tid << 6) + (v8 << 3) + (j << 1) + hh;
                if (h > prefix16)       { int q = atomicAdd(&cgt, 1); if (q < MT)  gt_i[q] = point_of(s); }
                else if (h == prefix16) { int q = atomicAdd(&ceq, 1); if (q < 256) eqbuf[q] = point_of(s); }
            }
        }
    }
    __syncthreads();
    const int ngt = (cgt < MT) ? cgt : MT;
    if (tid < ngt) gt_u[tid] = fmap(pert[base + gt_i[tid]]);
    __shared__ unsigned long long key256[256];
    if (ceq <= 256) {
        key256[tid] = (tid < ceq)
            ? (((unsigned long long)fmap(pert[base + eqbuf[tid]]) << 32) | (unsigned)(~eqbuf[tid]))
            : 0ull;
        __syncthreads();
        for (int k = 2; k <= 256; k <<= 1)
            for (int j = k >> 1; j > 0; j >>= 1) {
                const int l = tid ^ j;
                if (l > tid) {
                    const unsigned long long a = key256[tid], b = key256[l];
                    const bool up = ((tid & k) == 0);
                    if (up ? (a < b) : (a > b)) { key256[tid] = b; key256[l] = a; }
                }
                __syncthreads();
            }
    } else if (tid == 0) {
        unsigned long long sel[MT];
        int n = 0;
        for (int p = 0; p < PPE; ++p) {
            if (d16[slot_of(p)] != (unsigned short)prefix16) continue;
            const unsigned long long kk =
                ((unsigned long long)fmap(pert[base + p]) << 32) | (unsigned)(~p);
            if (n < need) {
                int j = n++;
                while (j > 0 && sel[j - 1] < kk) { sel[j] = sel[j - 1]; --j; }
                sel[j] = kk;
            } else if (kk > sel[need - 1]) {
                int j = need - 1;
                while (j > 0 && sel[j - 1] < kk) { sel[j] = sel[j - 1]; --j; }
                sel[j] = kk;
            }
        }
        for (int j = 0; j < need; ++j) key256[j] = sel[j];
    }
    __syncthreads();
    __shared__ unsigned long long key[MT];
    if (tid < MT) {
        if (tid < ngt)
            key[tid] = ((unsigned long long)gt_u[tid] << 32) | (unsigned)(~gt_i[tid]);
        else if (tid < ngt + need)
            key[tid] = key256[tid - ngt];
        else
            key[tid] = 0ull;
    }
    __syncthreads();
    for (int k = 2; k <= MT; k <<= 1)
        for (int j = k >> 1; j > 0; j >>= 1) {
            if (tid < MT) {
                const int l = tid ^ j;
                if (l > tid) {
                    const unsigned long long a = key[tid], b = key[l];
                    const bool up = ((tid & k) == 0);
                    if (up ? (a < b) : (a > b)) { key[tid] = b; key[l] = a; }
                }
            }
            __syncthreads();
        }
    if (tid < MT) {
        const int idx = (int)(~(unsigned)(key[tid] & 0xFFFFFFFFu));
        *(float4*)&centf[(long)(e * MT + tid) * 4] = c4f[base + idx];
    }
}

// ---------------------------------------------------------------------------
// 16-NN per (event,centroid): same structure, ascending
// ---------------------------------------------------------------------------
__device__ __forceinline__ unsigned d2bits(const float4 x, float c0, float c1,
                                           float c2, float c3) {
    const float q0 = __fmul_rn(c0 - x.x, c0 - x.x);
    const float q1 = __fmul_rn(c1 - x.y, c1 - x.y);
    const float q2 = __fmul_rn(c2 - x.z, c2 - x.z);
    const float q3 = __fmul_rn(c3 - x.w, c3 - x.w);
    return __float_as_uint(__fadd_rn(__fadd_rn(__fadd_rn(q0, q1), q2), q3));
}

__global__ __launch_bounds__(256) void knn_kernel(const float4* __restrict__ c4f,
                                                  const float* __restrict__ centf,
                                                  int* __restrict__ knn_idx)
{
    const int blk = blockIdx.x, tid = threadIdx.x;
    const int e = blk >> 7, base = e * PPE;
    const int wave = tid >> 6;
    const float c0 = centf[(long)blk * 4 + 0];
    const float c1 = centf[(long)blk * 4 + 1];
    const float c2 = centf[(long)blk * 4 + 2];
    const float c3 = centf[(long)blk * 4 + 3];
    __shared__ unsigned short d16[PPE];
    __shared__ unsigned histw[4 * HSTR];
    __shared__ int sh_need; __shared__ unsigned sh_b;
    for (int w = 0; w < 4; ++w) histw[w * HSTR + tid] = 0;
    __syncthreads();
    {
        unsigned pk[4];
        for (int i = 0; i < 64; ++i) {
            const int p = tid + (i << 8);
            const unsigned u = d2bits(c4f[base + p], c0, c1, c2, c3);
            const unsigned hw = u >> 16;
            if (i & 1) pk[(i & 7) >> 1] |= hw << 16; else pk[(i & 7) >> 1] = hw;
            atomicAdd(&histw[wave * HSTR + (u >> 24)], 1u);
            if ((i & 7) == 7)
                *(int4*)&d16[(tid << 6) + (i & ~7)] =
                    make_int4((int)pk[0], (int)pk[1], (int)pk[2], (int)pk[3]);
        }
    }
    __syncthreads();
    if (tid == 0) {
        int cum = 0, b = 0;
        for (; b < 255; ++b) {
            cum += (int)(histw[b] + histw[HSTR + b] + histw[2 * HSTR + b] + histw[3 * HSTR + b]);
            if (cum >= KNN) break;
        }
        if (cum < KNN) { cum += (int)(histw[255] + histw[HSTR + 255] + histw[2 * HSTR + 255] + histw[3 * HSTR + 255]); b = 255; }
        sh_need = KNN - (cum - (int)(histw[b] + histw[HSTR + b] + histw[2 * HSTR + b] + histw[3 * HSTR + b]));
        sh_b = (unsigned)b;
    }
    __syncthreads();
    int need = sh_need;
    const unsigned b1v = sh_b;
    __syncthreads();
    for (int w = 0; w < 4; ++w) histw[w * HSTR + tid] = 0;
    __syncthreads();
    for (int v8 = 0; v8 < 8; ++v8) {
        const int4 v = *(const int4*)&d16[(tid << 6) + (v8 << 3)];
        const unsigned uu[4] = {(unsigned)v.x, (unsigned)v.y, (unsigned)v.z, (unsigned)v.w};
#pragma unroll
        for (int j = 0; j < 4; ++j) {
            const unsigned h0 = uu[j] & 0xFFFFu, h1 = uu[j] >> 16;
            if ((h0 >> 8) == b1v) atomicAdd(&histw[wave * HSTR + (h0 & 255u)], 1u);
            if ((h1 >> 8) == b1v) atomicAdd(&histw[wave * HSTR + (h1 & 255u)], 1u);
        }
    }
    __syncthreads();
    if (tid == 0) {
        int cum = 0, b = 0;
        for (; b < 255; ++b) {
            cum += (int)(histw[b] + histw[HSTR + b] + histw[2 * HSTR + b] + histw[3 * HSTR + b]);
            if (cum >= need) break;
        }
        if (cum < need) { cum += (int)(histw[255] + histw[HSTR + 255] + histw[2 * HSTR + 255] + histw[3 * HSTR + 255]); b = 255; }
        sh_need = need - (cum - (int)(histw[b] + histw[HSTR + b] + histw[2 * HSTR + b] + histw[3 * HSTR + b]));
        sh_b = (unsigned)b;
    }
    __syncthreads();
    need = sh_need;
    const unsigned prefix16 = (b1v << 8) | sh_b;
    __shared__ int lt_i[KNN];
    __shared__ unsigned lt_u[KNN];
    __shared__ int eqbuf[256];
    __shared__ int clt, ceq;
    if (tid == 0) { clt = 0; ceq = 0; }
    __syncthreads();
    for (int v8 = 0; v8 < 8; ++v8) {
        const int4 v = *(const int4*)&d16[(tid << 6) + (v8 << 3)];
        const unsigned uu[4] = {(unsigned)v.x, (unsigned)v.y, (unsigned)v.z, (unsigned)v.w};
#pragma unroll
        for (int j = 0; j < 4; ++j) {
#pragma unroll
            for (int hh = 0; hh < 2; ++hh) {
                const unsigned h = hh ? (uu[j] >> 16) : (uu[j] & 0xFFFFu);
                const int s = (tid << 6) + (v8 << 3) + (j << 1) + hh;
                if (h < prefix16)       { int q = atomicAdd(&clt, 1); if (q < KNN) lt_i[q] = point_of(s); }
                else if (h == prefix16) { int q = atomicAdd(&ceq, 1); if (q < 256) eqbuf[q] = point_of(s); }
            }
        }
    }
    __syncthreads();
    const int nlt = (clt < KNN) ? clt : KNN;
    if (tid < nlt) lt_u[tid] = d2bits(c4f[base + lt_i[tid]], c0, c1, c2, c3);
    __shared__ unsigned long long key256[256];
    if (ceq <= 256) {
        key256[tid] = (tid < ceq)
            ? (((unsigned long long)d2bits(c4f[base + eqbuf[tid]], c0, c1, c2, c3) << 32)
               | (unsigned)eqbuf[tid])
            : 0xFFFFFFFFFFFFFFFFull;
        __syncthreads();
        for (int k = 2; k <= 256; k <<= 1)
            for (int j = k >> 1; j > 0; j >>= 1) {
                const int l = tid ^ j;
                if (l > tid) {
                    const unsigned long long a = key256[tid], b = key256[l];
                    const bool up = ((tid & k) == 0);
                    if (up ? (a > b) : (a < b)) { key256[tid] = b; key256[l] = a; }
                }
                __syncthreads();
            }
    } else if (tid == 0) {
        unsigned long long sel[KNN];
        int n = 0;
        for (int p = 0; p < PPE; ++p) {
            if (d16[slot_of(p)] != (unsigned short)prefix16) continue;
            const unsigned long long kk =
                ((unsigned long long)d2bits(c4f[base + p], c0, c1, c2, c3) << 32) | (unsigned)p;
            if (n < need) {
                int j = n++;
                while (j > 0 && sel[j - 1] > kk) { sel[j] = sel[j - 1]; --j; }
                sel[j] = kk;
            } else if (kk < sel[need - 1]) {
                int j = need - 1;
                while (j > 0 && sel[j - 1] > kk) { sel[j] = sel[j - 1]; --j; }
                sel[j] = kk;
            }
        }
        for (int j = 0; j < need; ++j) key256[j] = sel[j];
    }
    __syncthreads();
    if (tid == 0) {
        unsigned long long fin[KNN];
        int n = 0;
        for (int i = 0; i < nlt; ++i) {
            const unsigned long long kk = ((unsigned long long)lt_u[i] << 32) | (unsigned)lt_i[i];
            int j = n++;
            while (j > 0 && fin[j - 1] > kk) { fin[j] = fin[j - 1]; --j; }
            fin[j] = kk;
        }
        for (int i = 0; i < need; ++i) {
            const unsigned long long kk = key256[i];
            int j = n++;
            while (j > 0 && fin[j - 1] > kk) { fin[j] = fin[j - 1]; --j; }
            fin[j] = kk;
        }
        for (int r = 0; r < KNN; ++r)
            knn_idx[blk * KNN + r] = base + (int)(unsigned)(fin[r] & 0xFFFFFFFFu);
    }
}

// ---------------------------------------------------------------------------
// emit parallel: grid (BATCH, 16)
// ---------------------------------------------------------------------------
__global__ __launch_bounds__(256) void emit_kernel(const float* __restrict__ centf,
                                                   const float* __restrict__ tokf,
                                                   float* __restrict__ out,
                                                   long out_size)
{
    const int e = blockIdx.x, s = blockIdx.y, tid = threadIdx.x;
    __shared__ float tv[MT];
    __shared__ int   rk[MT];
    if (tid < MT) tv[tid] = centf[(long)(e * MT + tid) * 4 + 3];
    __syncthreads();
    if (tid < MT) {
        const float t = tv[tid]; int r = 0;
        for (int j = 0; j < MT; ++j)
            r += (tv[j] < t || (tv[j] == t && j < tid)) ? 1 : 0;
        rk[tid] = r;
    }
    __syncthreads();
    const long cent_off = (long)BATCH * MT * TOKD;
    const long mask_off = cent_off + (long)BATCH * MT * 4;
    for (int i = s * 8; i < s * 8 + 8; ++i) {
        const float* src = tokf + ((size_t)e * MT + i) * TOKD;
        const long dst = ((long)e * MT + rk[i]) * TOKD;
        for (int t4 = tid; t4 < TOKD / 4; t4 += 256) {
            const float4 v = ((const float4*)src)[t4];
            const long g = dst + (long)t4 * 4;
            if (g + 3 < out_size) {
                *(float4*)&out[g] = v;
            } else {
                if (g + 0 < out_size) out[g + 0] = v.x;
                if (g + 1 < out_size) out[g + 1] = v.y;
                if (g + 2 < out_size) out[g + 2] = v.z;
                if (g + 3 < out_size) out[g + 3] = v.w;
            }
        }
    }
    if (s == 0) {
        for (int idx = tid; idx < MT * 4; idx += 256) {
            const int i = idx >> 2, d = idx & 3;
            const long g = cent_off + ((long)e * MT + rk[i]) * 4 + d;
            if (g < out_size) out[g] = centf[((long)e * MT + i) * 4 + d];
        }
        for (int idx = tid; idx < MT; idx += 256) {
            const long g = mask_off + (long)e * MT + idx;
            if (g < out_size) out[g] = 1.0f;
        }
    }
}

// ---------------------------------------------------------------------------
extern "C" void kernel_launch(void* const* d_in, const int* in_sizes, int n_in,
                              void* d_out, int out_size, void* d_ws, size_t ws_size,
                              hipStream_t stream)
{
    const float* coords = (const float*)d_in[0];
    const float* feats  = (const float*)d_in[1];
    const float* lt     = (const float*)d_in[2];
    const float* w1  = (const float*)d_in[3];  const float* b1  = (const float*)d_in[4];
    const float* w2  = (const float*)d_in[5];  const float* b2  = (const float*)d_in[6];
    const float* w3  = (const float*)d_in[7];  const float* b3  = (const float*)d_in[8];
    const float* w4  = (const float*)d_in[9];  const float* b4  = (const float*)d_in[10];
    const float* iw1 = (const float*)d_in[11]; const float* ib1 = (const float*)d_in[12];
    const float* lng = (const float*)d_in[13]; const float* lnb = (const float*)d_in[14];
    const float* iw2 = (const float*)d_in[15]; const float* ib2 = (const float*)d_in[16];
    const float* iw3 = (const float*)d_in[17]; const float* ib3 = (const float*)d_in[18];
    const float* nw1 = (const float*)d_in[19]; const float* nb1 = (const float*)d_in[20];
    const float* nw2 = (const float*)d_in[21]; const float* nb2 = (const float*)d_in[22];
    const float* noise = (const float*)d_in[23];

    const int NBR = BATCH * MT * KNN;   // 16384
    // fixed floats: pert, centf, knn, pooled, c4f, bias45, T1, T2
    const size_t FIXED_FL = (size_t)NPT + 4096 + 16384 + (size_t)1024 * TOKD
                          + (size_t)NPT * 4 + 256 + 2 * (size_t)1024 * TOKD;
    const size_t s_w2 = 512 * 256,  s_w3 = 768 * 512,  s_w4 = 768 * 768;
    const size_t s_45 = 256 * 800,  s_i2 = 256 * 256;
    const size_t s_n1 = 768 * 768,  s_n2 = 768 * 768;
    const size_t WTOT = 2 * (s_w2 + s_w3 + s_w4 + s_45 + s_i2 + s_n1 + s_n2);
    const size_t BASE_BYTES = FIXED_FL * 4 + WTOT * 2;
    const size_t PERROW = 8448;
    int ch = 128;
    while (ch < NPT && BASE_BYTES + (size_t)(ch * 2) * PERROW <= ws_size) ch <<= 1;
    const size_t H3_BYTES = (size_t)NPT * 768 * 2;
    const bool persist = (BASE_BYTES + (size_t)ch * PERROW + H3_BYTES) <= ws_size;

    float*  pert   = (float*)d_ws;
    float*  centf  = pert + NPT;
    int*    knn    = (int*)(centf + 4096);
    float*  pooled = (float*)(knn + 16384);
    float4* c4f    = (float4*)(pooled + (size_t)1024 * TOKD);
    float*  bias45 = (float*)(c4f + NPT);
    float*  T1     = bias45 + 256;                      // 1024*768
    float*  T2     = T1 + (size_t)1024 * TOKD;          // 1024*768
    short*  wsp    = (short*)(T2 + (size_t)1024 * TOKD);
    short* w2h = wsp;            short* w2l = w2h + s_w2;
    short* w3h = w2l + s_w2;     short* w3l = w3h + s_w3;
    short* w4h = w3l + s_w3;     short* w4l = w4h + s_w4;
    short* f45h = w4l + s_w4;    short* f45l = f45h + s_45;
    short* i2h = f45l + s_45;    short* i2l = i2h + s_i2;
    short* n1h = i2l + s_i2;     short* n1l = n1h + s_n1;
    short* n2h = n1l + s_n1;     short* n2l = n2h + s_n2;
    short* PAh = n2l + s_n2;     short* PAl = PAh + (size_t)ch * 800;
    short* PBh = PAl + (size_t)ch * 800;
    short* PBl = PBh + (size_t)ch * 800;
    float* F2  = (float*)(PBl + (size_t)ch * 800);      // ch*256 fp32 (z1)
    float* F1z = F2 + (size_t)ch * 256;                 // ch*256 fp32 (z2)
    short* H3  = (short*)(F1z + (size_t)ch * 256);      // NPT*768 bf16-hi (opt)

    prep_kernel<<<dim3((NPT + 255) / 256), dim3(256), 0, stream>>>(coords, c4f);
    wsplit_kernel<<<dim3(512), dim3(256), 0, stream>>>(w2, 256, 512, 256, w2h, w2l);
    wsplit_kernel<<<dim3(768), dim3(256), 0, stream>>>(w3, 512, 768, 512, w3h, w3l);
    wsplit_kernel<<<dim3(768), dim3(256), 0, stream>>>(w4, 768, 768, 768, w4h, w4l);
    wsplit_kernel<<<dim3(256), dim3(256), 0, stream>>>(iw2, 256, 256, 256, i2h, i2l);
    wsplit_kernel<<<dim3(768), dim3(256), 0, stream>>>(nw1, 768, 768, 768, n1h, n1l);
    wsplit_kernel<<<dim3(768), dim3(256), 0, stream>>>(nw2, 768, 768, 768, n2h, n2l);
    w45_kernel<<<dim3(256), dim3(256), 0, stream>>>(w4, iw1, b4, ib1, f45h, f45l, bias45);

    for (int ck = 0; ck < NPT / ch; ++ck) {
        const int base = ck * ch;
        l1_kernel<<<dim3(ch / 64), dim3(256), 0, stream>>>(feats, w1, b1, PAh, PAl, base, nullptr);
        gemm_mf<<<dim3(512 / 128, ch / 128), dim3(256), 0, stream>>>(
            PAh, PAl, nullptr, 256, w2h, w2l, b2, PBh, PBl, 512, nullptr, nullptr, nullptr, 512, 1);
        gemm_mf<<<dim3(768 / 128, ch / 128), dim3(256), 0, stream>>>(
            PBh, PBl, nullptr, 512, w3h, w3l, b3, PAh, PAl, 800, nullptr,
            persist ? (H3 + (size_t)base * 768) : nullptr, nullptr, 768, 1);
        a2fill_kernel<<<dim3((ch * 32 + 255) / 256), dim3(256), 0, stream>>>(
            coords, base, ch, PAh, PAl);
        gemm_mf<<<dim3(256 / 128, ch / 128), dim3(256), 0, stream>>>(
            PAh, PAl, nullptr, 800, f45h, f45l, bias45, nullptr, nullptr, 0, F2, nullptr, nullptr, 256, 1);
        ln_kernel<<<dim3(ch / 32), dim3(256), 0, stream>>>(F2, lng, lnb, PBh, PBl);
        gemm_mf<<<dim3(256 / 128, ch / 128), dim3(256), 0, stream>>>(
            PBh, PBl, nullptr, 256, i2h, i2l, ib2, nullptr, nullptr, 0, F1z, nullptr, nullptr, 256, 1);
        imp_kernel<<<dim3(ch / 32), dim3(256), 0, stream>>>(F1z, iw3, ib3, noise, lt, pert, base);
    }

    topk_kernel<<<dim3(BATCH), dim3(256), 0, stream>>>(pert, c4f, centf);
    knn_kernel<<<dim3(BATCH * MT), dim3(256), 0, stream>>>(c4f, centf, knn);

    const int rcch = (ch < NBR) ? ch : NBR;
    for (int rc = 0; rc < NBR / rcch; ++rc) {
        if (persist) {
            gather_h3_kernel<<<dim3(rcch), dim3(256), 0, stream>>>(
                H3, knn, rc * rcch, PAh);
            gemm_mf<<<dim3(768 / 128, rcch / 128), dim3(256), 0, stream>>>(
                PAh, nullptr, nullptr, 768, w4h, w4l, b4, nullptr, nullptr, 0,
                nullptr, nullptr, pooled + (size_t)(rc * rcch / 16) * 768, 768, 0);
        } else {
            l1_kernel<<<dim3(rcch / 64), dim3(256), 0, stream>>>(feats, w1, b1, PAh, PAl, 0, knn + (size_t)rc * rcch);
            gemm_mf<<<dim3(512 / 128, rcch / 128), dim3(256), 0, stream>>>(
                PAh, PAl, nullptr, 256, w2h, w2l, b2, PBh, PBl, 512, nullptr, nullptr, nullptr, 512, 1);
            gemm_mf<<<dim3(768 / 128, rcch / 128), dim3(256), 0, stream>>>(
                PBh, PBl, nullptr, 512, w3h, w3l, b3, PAh, PAl, 768, nullptr, nullptr, nullptr, 768, 1);
            gemm_mf<<<dim3(768 / 128, rcch / 128), dim3(256), 0, stream>>>(
                PAh, PAl, nullptr, 768, w4h, w4l, b4, nullptr, nullptr, 0,
                nullptr, nullptr, pooled + (size_t)(rc * rcch / 16) * 768, 768, 0);
        }
    }

    // ---- token MLP (1024x768, fp32-A) + parallel emit ----
    gemm_mf<<<dim3(768 / 128, 1024 / 128), dim3(256), 0, stream>>>(
        nullptr, nullptr, pooled, 768, n1h, n1l, nb1, nullptr, nullptr, 0, T1, nullptr, nullptr, 768, 1);
    gemm_mf<<<dim3(768 / 128, 1024 / 128), dim3(256), 0, stream>>>(
        nullptr, nullptr, T1, 768, n2h, n2l, nb2, nullptr, nullptr, 0, T2, nullptr, nullptr, 768, 0);
    emit_kernel<<<dim3(BATCH, 16), dim3(256), 0, stream>>>(
        centf, T2, (float*)d_out, (long)out_size);
}

// Round 18
// 2210.345 us; speedup vs baseline: 1.0315x; 1.0315x over previous
//
#include <hip/hip_runtime.h>
#include <hip/hip_bf16.h>

// GumbelSoftmaxTokenizer: B=8, P=16384, FEAT=6, TOK=768, MT=128, K=16, IH=256
// All inputs float32; output buffer float32 (tokens, cents, masks concat).
#define NPT   131072      // B*P
#define BATCH 8
#define PPE   16384
#define MT    128
#define KNN   16
#define TOKD  768

typedef short bf16x8 __attribute__((ext_vector_type(8)));
typedef float f32x4  __attribute__((ext_vector_type(4)));

#define GL16(g, l) __builtin_amdgcn_global_load_lds(                         \
    (const __attribute__((address_space(1))) void*)(g),                      \
    (__attribute__((address_space(3))) void*)(l), 16, 0, 0)

__device__ __forceinline__ unsigned pack_hi(unsigned u0, unsigned u1) {
    return (u0 >> 16) | (u1 & 0xFFFF0000u);
}
__device__ __forceinline__ void split1(float x, short& h, short& l) {
    const unsigned u = __float_as_uint(x);
    h = (short)(u >> 16);
    const float r = x - __uint_as_float(u & 0xFFFF0000u);
    l = (short)(__float_as_uint(r) >> 16);
}

// ---------------------------------------------------------------------------
// prep: c4f[i] = coords[i,1:5] packed float4
// ---------------------------------------------------------------------------
__global__ __launch_bounds__(256) void prep_kernel(const float* __restrict__ coords,
                                                   float4* __restrict__ c4f)
{
    const int i = blockIdx.x * 256 + threadIdx.x;
    if (i < NPT) {
        const long b = (long)i * 5;
        c4f[i] = make_float4(coords[b + 1], coords[b + 2], coords[b + 3], coords[b + 4]);
    }
}

// ---------------------------------------------------------------------------
// Weight pre-convert: W(KxN f32) -> hi/lo [N][Kpad] bf16 (transposed, padded)
// ---------------------------------------------------------------------------
__global__ __launch_bounds__(256) void wsplit_kernel(const float* __restrict__ W,
                                                     int K, int N, int Kpad,
                                                     short* __restrict__ hi,
                                                     short* __restrict__ lo)
{
    const int n = blockIdx.x;
    for (int k = threadIdx.x; k < Kpad; k += 256) {
        short h = 0, l = 0;
        if (k < K) split1(W[(long)k * N + n], h, l);
        hi[(long)n * Kpad + k] = h;
        lo[(long)n * Kpad + k] = l;
    }
}

// ---------------------------------------------------------------------------
// W45 fusion: W45ext[N=256][Kpad=800] planes + bias45 (exact: L4 has no relu)
// ---------------------------------------------------------------------------
__global__ __launch_bounds__(256) void w45_kernel(const float* __restrict__ w4,
                                                  const float* __restrict__ iw1,
                                                  const float* __restrict__ b4,
                                                  const float* __restrict__ ib1,
                                                  short* __restrict__ hi,
                                                  short* __restrict__ lo,
                                                  float* __restrict__ bias45)
{
    const int n = blockIdx.x, tid = threadIdx.x;
    __shared__ float col[772];
    for (int j = tid; j < 772; j += 256) col[j] = iw1[(long)j * 256 + n];
    __syncthreads();
    for (int k = tid; k < 800; k += 256) {
        float v = 0.f;
        if (k < 768) {
            const float* wr = &w4[(long)k * 768];
            for (int j = 0; j < 768; ++j) v += wr[j] * col[j];
        } else if (k < 772) {
            v = col[k];
        }
        short h, l; split1(v, h, l);
        hi[(long)n * 800 + k] = h;
        lo[(long)n * 800 + k] = l;
    }
    float s = 0.f;
    for (int j = tid; j < 768; j += 256) s += b4[j] * col[j];
#pragma unroll
    for (int off = 32; off; off >>= 1) s += __shfl_down(s, off);
    __shared__ float part[4];
    if ((tid & 63) == 0) part[tid >> 6] = s;
    __syncthreads();
    if (tid == 0) bias45[n] = part[0] + part[1] + part[2] + part[3] + ib1[n];
}

// ---------------------------------------------------------------------------
// L1 multi-row: 64 rows/block
// ---------------------------------------------------------------------------
__global__ __launch_bounds__(256) void l1_kernel(const float* __restrict__ f,
                                                 const float* __restrict__ w1,
                                                 const float* __restrict__ b1,
                                                 short* __restrict__ hp,
                                                 short* __restrict__ lp,
                                                 int base,
                                                 const int* __restrict__ gather)
{
    const int r0 = blockIdx.x << 6, tid = threadIdx.x;
    float wc[6];
#pragma unroll
    for (int k = 0; k < 6; ++k) wc[k] = w1[k * 256 + tid];
    const float bb = b1[tid];
    for (int i = 0; i < 64; ++i) {
        const int r = r0 + i;
        int row = gather ? gather[r] : (base + r);
        row = (row < 0) ? 0 : ((row >= NPT) ? (NPT - 1) : row);
        float acc = bb;
#pragma unroll
        for (int k = 0; k < 6; ++k) acc += f[(long)row * 6 + k] * wc[k];
        acc = fmaxf(acc, 0.f);
        short h, l; split1(acc, h, l);
        hp[(long)r * 256 + tid] = h;
        lp[(long)r * 256 + tid] = l;
    }
}

// ---------------------------------------------------------------------------
// a2fill: plane cols 768..799 (stride 800)
// ---------------------------------------------------------------------------
__global__ __launch_bounds__(256) void a2fill_kernel(const float* __restrict__ coords,
                                                     int base, int ch,
                                                     short* __restrict__ hp,
                                                     short* __restrict__ lp)
{
    const int idx = blockIdx.x * 256 + threadIdx.x;
    if (idx >= ch * 32) return;
    const int r = idx >> 5, c = idx & 31;
    short h = 0, l = 0;
    if (c < 4) split1(coords[(long)(base + r) * 5 + 1 + c], h, l);
    hp[(long)r * 800 + 768 + c] = h;
    lp[(long)r * 800 + 768 + c] = l;
}

// ---------------------------------------------------------------------------
// gather_h3: G[i][0:768] = H3[knn[off+i]][0:768]
// ---------------------------------------------------------------------------
__global__ __launch_bounds__(256) void gather_h3_kernel(const short* __restrict__ H3,
                                                        const int* __restrict__ knn_idx,
                                                        int off,
                                                        short* __restrict__ G)
{
    const int i = blockIdx.x;
    const int row = knn_idx[off + i];
    const int4* src = (const int4*)(H3 + (long)row * 768);
    int4* dst = (int4*)(G + (long)i * 768);
    if (threadIdx.x < 96) dst[threadIdx.x] = src[threadIdx.x];
}

// ---------------------------------------------------------------------------
// Split-bf16 MFMA GEMM with optional fused 16-row-group max-pool (Cpool).
// ---------------------------------------------------------------------------
__global__ __launch_bounds__(256) void gemm_mf(
    const short* __restrict__ Aph, const short* __restrict__ Apl,
    const float* __restrict__ Afp, int Kpad,
    const short* __restrict__ Wth, const short* __restrict__ Wtl,
    const float* __restrict__ bias,
    short* __restrict__ Cph, short* __restrict__ Cpl, int KpadOut,
    float* __restrict__ Cf, short* __restrict__ Cp768,
    float* __restrict__ Cpool,
    int N, int relu)
{
    __shared__ short Ah[128 * 32];
    __shared__ short Al[128 * 32];
    __shared__ short Bh[128 * 32];
    __shared__ short Bl[128 * 32];
    const int tid = threadIdx.x;
    int rowb, colb;
    {
        const int ncol = gridDim.x, nrow = gridDim.y;
        if ((nrow & 7) == 0) {
            const int id  = blockIdx.y * ncol + blockIdx.x;
            const int sgs = ncol << 3;
            const int sg = id / sgs, wi = id % sgs;
            rowb = (sg << 3) + (wi & 7);
            colb = wi >> 3;
        } else { rowb = blockIdx.y; colb = blockIdx.x; }
    }
    const int row0 = rowb << 7, col0 = colb << 7;
    const int wave = tid >> 6, lane = tid & 63;
    const int q = lane >> 4, l16 = lane & 15;
    const int l2 = lane >> 2;
    const int ks = (lane & 3) << 3;

    f32x4 acc[2][8];
#pragma unroll
    for (int mt = 0; mt < 2; ++mt)
#pragma unroll
        for (int nt = 0; nt < 8; ++nt)
            acc[mt][nt] = (f32x4){0.f, 0.f, 0.f, 0.f};

    const int nk = Kpad >> 5;
    for (int t = 0; t < nk; ++t) {
        const int k0 = t << 5;
#pragma unroll
        for (int i = 0; i < 2; ++i) {
            const int mb = (wave << 5) + (i << 4);
            const long gb = (long)(col0 + mb + l2) * Kpad + k0 + ks;
            GL16(&Wth[gb], &Bh[mb * 32]);
            GL16(&Wtl[gb], &Bl[mb * 32]);
        }
        if (Aph) {
#pragma unroll
            for (int i = 0; i < 2; ++i) {
                const int mb = (wave << 5) + (i << 4);
                const long ga = (long)(row0 + mb + l2) * Kpad + k0 + ks;
                GL16(&Aph[ga], &Ah[mb * 32]);
                if (Apl) GL16(&Apl[ga], &Al[mb * 32]);
            }
        } else {
#pragma unroll
            for (int s = 0; s < 4; ++s) {
                const int l  = (s << 8) + tid;
                const int m  = l >> 3;
                const int k4 = (l & 7) << 2;
                const float4 v = *(const float4*)&Afp[(long)(row0 + m) * Kpad + k0 + k4];
                const unsigned u0 = __float_as_uint(v.x), u1 = __float_as_uint(v.y);
                const unsigned u2 = __float_as_uint(v.z), u3 = __float_as_uint(v.w);
                const unsigned r0 = __float_as_uint(v.x - __uint_as_float(u0 & 0xFFFF0000u));
                const unsigned r1 = __float_as_uint(v.y - __uint_as_float(u1 & 0xFFFF0000u));
                const unsigned r2 = __float_as_uint(v.z - __uint_as_float(u2 & 0xFFFF0000u));
                const unsigned r3 = __float_as_uint(v.w - __uint_as_float(u3 & 0xFFFF0000u));
                *(int2*)&Ah[m * 32 + k4] = make_int2((int)pack_hi(u0, u1), (int)pack_hi(u2, u3));
                *(int2*)&Al[m * 32 + k4] = make_int2((int)pack_hi(r0, r1), (int)pack_hi(r2, r3));
            }
        }
        __syncthreads();
        const bool useAl = (Apl != nullptr) || (Aph == nullptr);
        bf16x8 ah[2], al[2];
#pragma unroll
        for (int mt = 0; mt < 2; ++mt) {
            const int mrow = (wave << 5) + (mt << 4) + l16;
            ah[mt] = *(const bf16x8*)&Ah[mrow * 32 + (q << 3)];
            if (useAl) al[mt] = *(const bf16x8*)&Al[mrow * 32 + (q << 3)];
        }
#pragma unroll
        for (int nt = 0; nt < 8; ++nt) {
            const int ncol2 = (nt << 4) + l16;
            const bf16x8 bh = *(const bf16x8*)&Bh[ncol2 * 32 + (q << 3)];
            const bf16x8 bl = *(const bf16x8*)&Bl[ncol2 * 32 + (q << 3)];
#pragma unroll
            for (int mt = 0; mt < 2; ++mt) {
                acc[mt][nt] = __builtin_amdgcn_mfma_f32_16x16x32_bf16(ah[mt], bh, acc[mt][nt], 0, 0, 0);
                acc[mt][nt] = __builtin_amdgcn_mfma_f32_16x16x32_bf16(ah[mt], bl, acc[mt][nt], 0, 0, 0);
                if (useAl)
                    acc[mt][nt] = __builtin_amdgcn_mfma_f32_16x16x32_bf16(al[mt], bh, acc[mt][nt], 0, 0, 0);
            }
        }
        __syncthreads();
    }
    if (Cpool) {
#pragma unroll
        for (int mt = 0; mt < 2; ++mt)
#pragma unroll
            for (int nt = 0; nt < 8; ++nt) {
                const int col = col0 + (nt << 4) + l16;
                float m = fmaxf(fmaxf(acc[mt][nt][0], acc[mt][nt][1]),
                                fmaxf(acc[mt][nt][2], acc[mt][nt][3]));
                m = fmaxf(m, __shfl_xor(m, 16));
                m = fmaxf(m, __shfl_xor(m, 32));
                m += bias[col];
                if (relu) m = fmaxf(m, 0.f);
                if (q == 0)
                    Cpool[(long)((row0 >> 4) + (wave << 1) + mt) * 768 + col] = m;
            }
        return;
    }
#pragma unroll
    for (int mt = 0; mt < 2; ++mt)
#pragma unroll
        for (int nt = 0; nt < 8; ++nt) {
            const int col = col0 + (nt << 4) + l16;
            const float bs = bias[col];
#pragma unroll
            for (int rg = 0; rg < 4; ++rg) {
                const int row = row0 + (wave << 5) + (mt << 4) + (q << 2) + rg;
                float v = acc[mt][nt][rg] + bs;
                if (relu) v = fmaxf(v, 0.f);
                if (Cf) Cf[(long)row * N + col] = v;
                if (Cph || Cp768) {
                    short h, l; split1(v, h, l);
                    if (Cph) {
                        Cph[(long)row * KpadOut + col] = h;
                        Cpl[(long)row * KpadOut + col] = l;
                    }
                    if (Cp768) Cp768[(long)row * 768 + col] = h;
                }
            }
        }
}

// ---------------------------------------------------------------------------
// LayerNorm multi-row: wave per row x 8 rows
// ---------------------------------------------------------------------------
__global__ __launch_bounds__(256) void ln_kernel(const float* __restrict__ z,
                                                 const float* __restrict__ g,
                                                 const float* __restrict__ b,
                                                 short* __restrict__ hp,
                                                 short* __restrict__ lp)
{
    const int tid = threadIdx.x, wave = tid >> 6, lane = tid & 63;
    float gv[4], bv[4];
#pragma unroll
    for (int j = 0; j < 4; ++j) { gv[j] = g[lane * 4 + j]; bv[j] = b[lane * 4 + j]; }
    for (int i = 0; i < 8; ++i) {
        const int r = (blockIdx.x << 5) + (wave << 3) + i;
        const float4 x = *(const float4*)&z[(long)r * 256 + lane * 4];
        float s = x.x + x.y + x.z + x.w;
#pragma unroll
        for (int off = 32; off; off >>= 1) s += __shfl_down(s, off);
        const float mu = __shfl(s, 0) * (1.f / 256.f);
        const float d0 = x.x - mu, d1 = x.y - mu, d2 = x.z - mu, d3 = x.w - mu;
        float s2 = d0 * d0 + d1 * d1 + d2 * d2 + d3 * d3;
#pragma unroll
        for (int off = 32; off; off >>= 1) s2 += __shfl_down(s2, off);
        const float den = sqrtf(__shfl(s2, 0) * (1.f / 256.f) + 1e-5f);
        const float v[4] = { d0 / den * gv[0] + bv[0], d1 / den * gv[1] + bv[1],
                             d2 / den * gv[2] + bv[2], d3 / den * gv[3] + bv[3] };
#pragma unroll
        for (int j = 0; j < 4; ++j) {
            short h, l; split1(v[j], h, l);
            hp[(long)r * 256 + lane * 4 + j] = h;
            lp[(long)r * 256 + lane * 4 + j] = l;
        }
    }
}

// ---------------------------------------------------------------------------
// imp multi-row: wave per row x 8
// ---------------------------------------------------------------------------
__global__ __launch_bounds__(256) void imp_kernel(const float* __restrict__ z2,
                                                  const float* __restrict__ iw3,
                                                  const float* __restrict__ ib3,
                                                  const float* __restrict__ noise,
                                                  const float* __restrict__ lt,
                                                  float* __restrict__ pert,
                                                  int base)
{
    const int tid = threadIdx.x, wave = tid >> 6, lane = tid & 63;
    float wv[4];
#pragma unroll
    for (int j = 0; j < 4; ++j) wv[j] = iw3[lane * 4 + j];
    const float temp = fmaxf(expf(lt[0]), 0.1f);
    const float b3v = ib3[0];
    for (int i = 0; i < 8; ++i) {
        const int r = (blockIdx.x << 5) + (wave << 3) + i;
        const float4 x = *(const float4*)&z2[(long)r * 256 + lane * 4];
        float s = x.x * wv[0] + x.y * wv[1] + x.z * wv[2] + x.w * wv[3];
#pragma unroll
        for (int off = 32; off; off >>= 1) s += __shfl_down(s, off);
        if (lane == 0)
            pert[base + r] = (s + b3v + noise[base + r]) / temp;
    }
}

// ---------------------------------------------------------------------------
// top-128 per event: 2-level cached radix on fmap(pert) (R16 version)
// ---------------------------------------------------------------------------
__device__ __forceinline__ unsigned fmap(float f) {
    unsigned x = __float_as_uint(f);
    return (x & 0x80000000u) ? ~x : (x | 0x80000000u);
}

__global__ __launch_bounds__(256) void topk_kernel(const float* __restrict__ pert,
                                                   const float4* __restrict__ c4f,
                                                   float* __restrict__ centf)
{
    const int e = blockIdx.x, tid = threadIdx.x;
    const int base = e * PPE;
    __shared__ unsigned short d16[PPE];          // 32 KB
    __shared__ unsigned hist[256];
    __shared__ int sh_need; __shared__ unsigned sh_b;
    hist[tid] = 0;
    __syncthreads();
    for (int p = tid; p < PPE; p += 256) {
        const unsigned u = fmap(pert[base + p]);
        d16[p] = (unsigned short)(u >> 16);
        atomicAdd(&hist[u >> 24], 1u);
    }
    __syncthreads();
    if (tid == 0) {
        int cum = 0, b = 255;
        for (; b > 0; --b) { cum += (int)hist[b]; if (cum >= MT) break; }
        if (cum < MT) { cum += (int)hist[0]; b = 0; }
        sh_need = MT - (cum - (int)hist[b]); sh_b = (unsigned)b;
    }
    __syncthreads();
    int need = sh_need;
    const unsigned b1v = sh_b;
    __syncthreads();
    hist[tid] = 0;
    __syncthreads();
    for (int p = tid; p < PPE; p += 256) {
        const unsigned h = d16[p];
        if ((h >> 8) == b1v) atomicAdd(&hist[h & 255u], 1u);
    }
    __syncthreads();
    if (tid == 0) {
        int cum = 0, b = 255;
        for (; b > 0; --b) { cum += (int)hist[b]; if (cum >= need) break; }
        if (cum < need) { cum += (int)hist[0]; b = 0; }
        sh_need = need - (cum - (int)hist[b]); sh_b = (unsigned)b;
    }
    __syncthreads();
    need = sh_need;
    const unsigned prefix16 = (b1v << 8) | sh_b;
    __shared__ int gt_i[MT];
    __shared__ unsigned gt_u[MT];
    __shared__ int eqbuf[256];
    __shared__ int cgt, ceq;
    if (tid == 0) { cgt = 0; ceq = 0; }
    __syncthreads();
    for (int p = tid; p < PPE; p += 256) {
        const unsigned h = d16[p];
        if (h > prefix16)        { int q = atomicAdd(&cgt, 1); if (q < MT)  gt_i[q] = p; }
        else if (h == prefix16)  { int q = atomicAdd(&ceq, 1); if (q < 256) eqbuf[q] = p; }
    }
    __syncthreads();
    const int ngt = (cgt < MT) ? cgt : MT;
    if (tid < ngt) gt_u[tid] = fmap(pert[base + gt_i[tid]]);
    __shared__ unsigned long long key256[256];
    if (ceq <= 256) {
        key256[tid] = (tid < ceq)
            ? (((unsigned long long)fmap(pert[base + eqbuf[tid]]) << 32) | (unsigned)(~eqbuf[tid]))
            : 0ull;
        __syncthreads();
        for (int k = 2; k <= 256; k <<= 1)
            for (int j = k >> 1; j > 0; j >>= 1) {
                const int l = tid ^ j;
                if (l > tid) {
                    const unsigned long long a = key256[tid], b = key256[l];
                    const bool up = ((tid & k) == 0);
                    if (up ? (a < b) : (a > b)) { key256[tid] = b; key256[l] = a; }
                }
                __syncthreads();
            }
    } else if (tid == 0) {
        unsigned long long sel[MT];
        int n = 0;
        for (int p = 0; p < PPE; ++p) {
            if (d16[p] != (unsigned short)prefix16) continue;
            const unsigned long long kk =
                ((unsigned long long)fmap(pert[base + p]) << 32) | (unsigned)(~p);
            if (n < need) {
                int j = n++;
                while (j > 0 && sel[j - 1] < kk) { sel[j] = sel[j - 1]; --j; }
                sel[j] = kk;
            } else if (kk > sel[need - 1]) {
                int j = need - 1;
                while (j > 0 && sel[j - 1] < kk) { sel[j] = sel[j - 1]; --j; }
                sel[j] = kk;
            }
        }
        for (int j = 0; j < need; ++j) key256[j] = sel[j];
    }
    __syncthreads();
    __shared__ unsigned long long key[MT];
    if (tid < MT) {
        if (tid < ngt)
            key[tid] = ((unsigned long long)gt_u[tid] << 32) | (unsigned)(~gt_i[tid]);
        else if (tid < ngt + need)
            key[tid] = key256[tid - ngt];
        else
            key[tid] = 0ull;
    }
    __syncthreads();
    for (int k = 2; k <= MT; k <<= 1)
        for (int j = k >> 1; j > 0; j >>= 1) {
            if (tid < MT) {
                const int l = tid ^ j;
                if (l > tid) {
                    const unsigned long long a = key[tid], b = key[l];
                    const bool up = ((tid & k) == 0);
                    if (up ? (a < b) : (a > b)) { key[tid] = b; key[l] = a; }
                }
            }
            __syncthreads();
        }
    if (tid < MT) {
        const int idx = (int)(~(unsigned)(key[tid] & 0xFFFFFFFFu));
        *(float4*)&centf[(long)(e * MT + tid) * 4] = c4f[base + idx];
    }
}

// ---------------------------------------------------------------------------
// 16-NN per (event,centroid): 2-level cached radix on d2 bits (R16 version)
// ---------------------------------------------------------------------------
__device__ __forceinline__ unsigned d2bits(const float4 x, float c0, float c1,
                                           float c2, float c3) {
    const float q0 = __fmul_rn(c0 - x.x, c0 - x.x);
    const float q1 = __fmul_rn(c1 - x.y, c1 - x.y);
    const float q2 = __fmul_rn(c2 - x.z, c2 - x.z);
    const float q3 = __fmul_rn(c3 - x.w, c3 - x.w);
    return __float_as_uint(__fadd_rn(__fadd_rn(__fadd_rn(q0, q1), q2), q3));
}

__global__ __launch_bounds__(256) void knn_kernel(const float4* __restrict__ c4f,
                                                  const float* __restrict__ centf,
                                                  int* __restrict__ knn_idx)
{
    const int blk = blockIdx.x, tid = threadIdx.x;
    const int e = blk >> 7, base = e * PPE;
    const float c0 = centf[(long)blk * 4 + 0];
    const float c1 = centf[(long)blk * 4 + 1];
    const float c2 = centf[(long)blk * 4 + 2];
    const float c3 = centf[(long)blk * 4 + 3];
    __shared__ unsigned short d16[PPE];          // 32 KB
    __shared__ unsigned hist[256];
    __shared__ int sh_need; __shared__ unsigned sh_b;
    hist[tid] = 0;
    __syncthreads();
    for (int p = tid; p < PPE; p += 256) {
        const unsigned u = d2bits(c4f[base + p], c0, c1, c2, c3);
        d16[p] = (unsigned short)(u >> 16);
        atomicAdd(&hist[u >> 24], 1u);
    }
    __syncthreads();
    if (tid == 0) {
        int cum = 0, b = 0;
        for (; b < 255; ++b) { cum += (int)hist[b]; if (cum >= KNN) break; }
        if (cum < KNN) { cum += (int)hist[255]; b = 255; }
        sh_need = KNN - (cum - (int)hist[b]); sh_b = (unsigned)b;
    }
    __syncthreads();
    int need = sh_need;
    const unsigned b1v = sh_b;
    __syncthreads();
    hist[tid] = 0;
    __syncthreads();
    for (int p = tid; p < PPE; p += 256) {
        const unsigned h = d16[p];
        if ((h >> 8) == b1v) atomicAdd(&hist[h & 255u], 1u);
    }
    __syncthreads();
    if (tid == 0) {
        int cum = 0, b = 0;
        for (; b < 255; ++b) { cum += (int)hist[b]; if (cum >= need) break; }
        if (cum < need) { cum += (int)hist[255]; b = 255; }
        sh_need = need - (cum - (int)hist[b]); sh_b = (unsigned)b;
    }
    __syncthreads();
    need = sh_need;
    const unsigned prefix16 = (b1v << 8) | sh_b;
    __shared__ int lt_i[KNN];
    __shared__ unsigned lt_u[KNN];
    __shared__ int eqbuf[256];
    __shared__ int clt, ceq;
    if (tid == 0) { clt = 0; ceq = 0; }
    __syncthreads();
    for (int p = tid; p < PPE; p += 256) {
        const unsigned h = d16[p];
        if (h < prefix16)        { int q = atomicAdd(&clt, 1); if (q < KNN) lt_i[q] = p; }
        else if (h == prefix16)  { int q = atomicAdd(&ceq, 1); if (q < 256) eqbuf[q] = p; }
    }
    __syncthreads();
    const int nlt = (clt < KNN) ? clt : KNN;
    if (tid < nlt) lt_u[tid] = d2bits(c4f[base + lt_i[tid]], c0, c1, c2, c3);
    __shared__ unsigned long long key256[256];
    if (ceq <= 256) {
        key256[tid] = (tid < ceq)
            ? (((unsigned long long)d2bits(c4f[base + eqbuf[tid]], c0, c1, c2, c3) << 32)
               | (unsigned)eqbuf[tid])
            : 0xFFFFFFFFFFFFFFFFull;
        __syncthreads();
        for (int k = 2; k <= 256; k <<= 1)
            for (int j = k >> 1; j > 0; j >>= 1) {
                const int l = tid ^ j;
                if (l > tid) {
                    const unsigned long long a = key256[tid], b = key256[l];
                    const bool up = ((tid & k) == 0);
                    if (up ? (a > b) : (a < b)) { key256[tid] = b; key256[l] = a; }
                }
                __syncthreads();
            }
    } else if (tid == 0) {
        unsigned long long sel[KNN];
        int n = 0;
        for (int p = 0; p < PPE; ++p) {
            if (d16[p] != (unsigned short)prefix16) continue;
            const unsigned long long kk =
                ((unsigned long long)d2bits(c4f[base + p], c0, c1, c2, c3) << 32) | (unsigned)p;
            if (n < need) {
                int j = n++;
                while (j > 0 && sel[j - 1] > kk) { sel[j] = sel[j - 1]; --j; }
                sel[j] = kk;
            } else if (kk < sel[need - 1]) {
                int j = need - 1;
                while (j > 0 && sel[j - 1] > kk) { sel[j] = sel[j - 1]; --j; }
                sel[j] = kk;
            }
        }
        for (int j = 0; j < need; ++j) key256[j] = sel[j];
    }
    __syncthreads();
    if (tid == 0) {
        unsigned long long fin[KNN];
        int n = 0;
        for (int i = 0; i < nlt; ++i) {
            const unsigned long long kk = ((unsigned long long)lt_u[i] << 32) | (unsigned)lt_i[i];
            int j = n++;
            while (j > 0 && fin[j - 1] > kk) { fin[j] = fin[j - 1]; --j; }
            fin[j] = kk;
        }
        for (int i = 0; i < need; ++i) {
            const unsigned long long kk = key256[i];
            int j = n++;
            while (j > 0 && fin[j - 1] > kk) { fin[j] = fin[j - 1]; --j; }
            fin[j] = kk;
        }
        for (int r = 0; r < KNN; ++r)
            knn_idx[blk * KNN + r] = base + (int)(unsigned)(fin[r] & 0xFFFFFFFFu);
    }
}

// ---------------------------------------------------------------------------
// emit parallel: grid (BATCH, 16)
// ---------------------------------------------------------------------------
__global__ __launch_bounds__(256) void emit_kernel(const float* __restrict__ centf,
                                                   const float* __restrict__ tokf,
                                                   float* __restrict__ out,
                                                   long out_size)
{
    const int e = blockIdx.x, s = blockIdx.y, tid = threadIdx.x;
    __shared__ float tv[MT];
    __shared__ int   rk[MT];
    if (tid < MT) tv[tid] = centf[(long)(e * MT + tid) * 4 + 3];
    __syncthreads();
    if (tid < MT) {
        const float t = tv[tid]; int r = 0;
        for (int j = 0; j < MT; ++j)
            r += (tv[j] < t || (tv[j] == t && j < tid)) ? 1 : 0;
        rk[tid] = r;
    }
    __syncthreads();
    const long cent_off = (long)BATCH * MT * TOKD;
    const long mask_off = cent_off + (long)BATCH * MT * 4;
    for (int i = s * 8; i < s * 8 + 8; ++i) {
        const float* src = tokf + ((size_t)e * MT + i) * TOKD;
        const long dst = ((long)e * MT + rk[i]) * TOKD;
        for (int t4 = tid; t4 < TOKD / 4; t4 += 256) {
            const float4 v = ((const float4*)src)[t4];
            const long g = dst + (long)t4 * 4;
            if (g + 3 < out_size) {
                *(float4*)&out[g] = v;
            } else {
                if (g + 0 < out_size) out[g + 0] = v.x;
                if (g + 1 < out_size) out[g + 1] = v.y;
                if (g + 2 < out_size) out[g + 2] = v.z;
                if (g + 3 < out_size) out[g + 3] = v.w;
            }
        }
    }
    if (s == 0) {
        for (int idx = tid; idx < MT * 4; idx += 256) {
            const int i = idx >> 2, d = idx & 3;
            const long g = cent_off + ((long)e * MT + rk[i]) * 4 + d;
            if (g < out_size) out[g] = centf[((long)e * MT + i) * 4 + d];
        }
        for (int idx = tid; idx < MT; idx += 256) {
            const long g = mask_off + (long)e * MT + idx;
            if (g < out_size) out[g] = 1.0f;
        }
    }
}

// ---------------------------------------------------------------------------
extern "C" void kernel_launch(void* const* d_in, const int* in_sizes, int n_in,
                              void* d_out, int out_size, void* d_ws, size_t ws_size,
                              hipStream_t stream)
{
    const float* coords = (const float*)d_in[0];
    const float* feats  = (const float*)d_in[1];
    const float* lt     = (const float*)d_in[2];
    const float* w1  = (const float*)d_in[3];  const float* b1  = (const float*)d_in[4];
    const float* w2  = (const float*)d_in[5];  const float* b2  = (const float*)d_in[6];
    const float* w3  = (const float*)d_in[7];  const float* b3  = (const float*)d_in[8];
    const float* w4  = (const float*)d_in[9];  const float* b4  = (const float*)d_in[10];
    const float* iw1 = (const float*)d_in[11]; const float* ib1 = (const float*)d_in[12];
    const float* lng = (const float*)d_in[13]; const float* lnb = (const float*)d_in[14];
    const float* iw2 = (const float*)d_in[15]; const float* ib2 = (const float*)d_in[16];
    const float* iw3 = (const float*)d_in[17]; const float* ib3 = (const float*)d_in[18];
    const float* nw1 = (const float*)d_in[19]; const float* nb1 = (const float*)d_in[20];
    const float* nw2 = (const float*)d_in[21]; const float* nb2 = (const float*)d_in[22];
    const float* noise = (const float*)d_in[23];

    const int NBR = BATCH * MT * KNN;   // 16384
    // fixed floats: pert, centf, knn, pooled, c4f, bias45, T1, T2
    const size_t FIXED_FL = (size_t)NPT + 4096 + 16384 + (size_t)1024 * TOKD
                          + (size_t)NPT * 4 + 256 + 2 * (size_t)1024 * TOKD;
    const size_t s_w2 = 512 * 256,  s_w3 = 768 * 512,  s_w4 = 768 * 768;
    const size_t s_45 = 256 * 800,  s_i2 = 256 * 256;
    const size_t s_n1 = 768 * 768,  s_n2 = 768 * 768;
    const size_t WTOT = 2 * (s_w2 + s_w3 + s_w4 + s_45 + s_i2 + s_n1 + s_n2);
    const size_t BASE_BYTES = FIXED_FL * 4 + WTOT * 2;
    const size_t PERROW = 8448;
    int ch = 128;
    while (ch < NPT && BASE_BYTES + (size_t)(ch * 2) * PERROW <= ws_size) ch <<= 1;
    const size_t H3_BYTES = (size_t)NPT * 768 * 2;
    const bool persist = (BASE_BYTES + (size_t)ch * PERROW + H3_BYTES) <= ws_size;

    float*  pert   = (float*)d_ws;
    float*  centf  = pert + NPT;
    int*    knn    = (int*)(centf + 4096);
    float*  pooled = (float*)(knn + 16384);
    float4* c4f    = (float4*)(pooled + (size_t)1024 * TOKD);
    float*  bias45 = (float*)(c4f + NPT);
    float*  T1     = bias45 + 256;                      // 1024*768
    float*  T2     = T1 + (size_t)1024 * TOKD;          // 1024*768
    short*  wsp    = (short*)(T2 + (size_t)1024 * TOKD);
    short* w2h = wsp;            short* w2l = w2h + s_w2;
    short* w3h = w2l + s_w2;     short* w3l = w3h + s_w3;
    short* w4h = w3l + s_w3;     short* w4l = w4h + s_w4;
    short* f45h = w4l + s_w4;    short* f45l = f45h + s_45;
    short* i2h = f45l + s_45;    short* i2l = i2h + s_i2;
    short* n1h = i2l + s_i2;     short* n1l = n1h + s_n1;
    short* n2h = n1l + s_n1;     short* n2l = n2h + s_n2;
    short* PAh = n2l + s_n2;     short* PAl = PAh + (size_t)ch * 800;
    short* PBh = PAl + (size_t)ch * 800;
    short* PBl = PBh + (size_t)ch * 800;
    float* F2  = (float*)(PBl + (size_t)ch * 800);      // ch*256 fp32 (z1)
    float* F1z = F2 + (size_t)ch * 256;                 // ch*256 fp32 (z2)
    short* H3  = (short*)(F1z + (size_t)ch * 256);      // NPT*768 bf16-hi (opt)

    prep_kernel<<<dim3((NPT + 255) / 256), dim3(256), 0, stream>>>(coords, c4f);
    wsplit_kernel<<<dim3(512), dim3(256), 0, stream>>>(w2, 256, 512, 256, w2h, w2l);
    wsplit_kernel<<<dim3(768), dim3(256), 0, stream>>>(w3, 512, 768, 512, w3h, w3l);
    wsplit_kernel<<<dim3(768), dim3(256), 0, stream>>>(w4, 768, 768, 768, w4h, w4l);
    wsplit_kernel<<<dim3(256), dim3(256), 0, stream>>>(iw2, 256, 256, 256, i2h, i2l);
    wsplit_kernel<<<dim3(768), dim3(256), 0, stream>>>(nw1, 768, 768, 768, n1h, n1l);
    wsplit_kernel<<<dim3(768), dim3(256), 0, stream>>>(nw2, 768, 768, 768, n2h, n2l);
    w45_kernel<<<dim3(256), dim3(256), 0, stream>>>(w4, iw1, b4, ib1, f45h, f45l, bias45);

    for (int ck = 0; ck < NPT / ch; ++ck) {
        const int base = ck * ch;
        l1_kernel<<<dim3(ch / 64), dim3(256), 0, stream>>>(feats, w1, b1, PAh, PAl, base, nullptr);
        gemm_mf<<<dim3(512 / 128, ch / 128), dim3(256), 0, stream>>>(
            PAh, PAl, nullptr, 256, w2h, w2l, b2, PBh, PBl, 512, nullptr, nullptr, nullptr, 512, 1);
        gemm_mf<<<dim3(768 / 128, ch / 128), dim3(256), 0, stream>>>(
            PBh, PBl, nullptr, 512, w3h, w3l, b3, PAh, PAl, 800, nullptr,
            persist ? (H3 + (size_t)base * 768) : nullptr, nullptr, 768, 1);
        a2fill_kernel<<<dim3((ch * 32 + 255) / 256), dim3(256), 0, stream>>>(
            coords, base, ch, PAh, PAl);
        gemm_mf<<<dim3(256 / 128, ch / 128), dim3(256), 0, stream>>>(
            PAh, PAl, nullptr, 800, f45h, f45l, bias45, nullptr, nullptr, 0, F2, nullptr, nullptr, 256, 1);
        ln_kernel<<<dim3(ch / 32), dim3(256), 0, stream>>>(F2, lng, lnb, PBh, PBl);
        gemm_mf<<<dim3(256 / 128, ch / 128), dim3(256), 0, stream>>>(
            PBh, PBl, nullptr, 256, i2h, i2l, ib2, nullptr, nullptr, 0, F1z, nullptr, nullptr, 256, 1);
        imp_kernel<<<dim3(ch / 32), dim3(256), 0, stream>>>(F1z, iw3, ib3, noise, lt, pert, base);
    }

    topk_kernel<<<dim3(BATCH), dim3(256), 0, stream>>>(pert, c4f, centf);
    knn_kernel<<<dim3(BATCH * MT), dim3(256), 0, stream>>>(c4f, centf, knn);

    const int rcch = (ch < NBR) ? ch : NBR;
    for (int rc = 0; rc < NBR / rcch; ++rc) {
        if (persist) {
            gather_h3_kernel<<<dim3(rcch), dim3(256), 0, stream>>>(
                H3, knn, rc * rcch, PAh);
            gemm_mf<<<dim3(768 / 128, rcch / 128), dim3(256), 0, stream>>>(
                PAh, nullptr, nullptr, 768, w4h, w4l, b4, nullptr, nullptr, 0,
                nullptr, nullptr, pooled + (size_t)(rc * rcch / 16) * 768, 768, 0);
        } else {
            l1_kernel<<<dim3(rcch / 64), dim3(256), 0, stream>>>(feats, w1, b1, PAh, PAl, 0, knn + (size_t)rc * rcch);
            gemm_mf<<<dim3(512 / 128, rcch / 128), dim3(256), 0, stream>>>(
                PAh, PAl, nullptr, 256, w2h, w2l, b2, PBh, PBl, 512, nullptr, nullptr, nullptr, 512, 1);
            gemm_mf<<<dim3(768 / 128, rcch / 128), dim3(256), 0, stream>>>(
                PBh, PBl, nullptr, 512, w3h, w3l, b3, PAh, PAl, 768, nullptr, nullptr, nullptr, 768, 1);
            gemm_mf<<<dim3(768 / 128, rcch / 128), dim3(256), 0, stream>>>(
                PAh, PAl, nullptr, 768, w4h, w4l, b4, nullptr, nullptr, 0,
                nullptr, nullptr, pooled + (size_t)(rc * rcch / 16) * 768, 768, 0);
        }
    }

    // ---- token MLP (1024x768, fp32-A) + parallel emit ----
    gemm_mf<<<dim3(768 / 128, 1024 / 128), dim3(256), 0, stream>>>(
        nullptr, nullptr, pooled, 768, n1h, n1l, nb1, nullptr, nullptr, 0, T1, nullptr, nullptr, 768, 1);
    gemm_mf<<<dim3(768 / 128, 1024 / 128), dim3(256), 0, stream>>>(
        nullptr, nullptr, T1, 768, n2h, n2l, nb2, nullptr, nullptr, 0, T2, nullptr, nullptr, 768, 0);
    emit_kernel<<<dim3(BATCH, 16), dim3(256), 0, stream>>>(
        centf, T2, (float*)d_out, (long)out_size);
}

// Round 19
// 2142.595 us; speedup vs baseline: 1.0641x; 1.0316x over previous
//
#include <hip/hip_runtime.h>
#include <hip/hip_bf16.h>

// GumbelSoftmaxTokenizer: B=8, P=16384, FEAT=6, TOK=768, MT=128, K=16, IH=256
// All inputs float32; output buffer float32 (tokens, cents, masks concat).
#define NPT   131072      // B*P
#define BATCH 8
#define PPE   16384
#define MT    128
#define KNN   16
#define TOKD  768

typedef short bf16x8 __attribute__((ext_vector_type(8)));
typedef float f32x4  __attribute__((ext_vector_type(4)));

#define GL16(g, l) __builtin_amdgcn_global_load_lds(                         \
    (const __attribute__((address_space(1))) void*)(g),                      \
    (__attribute__((address_space(3))) void*)(l), 16, 0, 0)

__device__ __forceinline__ unsigned pack_hi(unsigned u0, unsigned u1) {
    return (u0 >> 16) | (u1 & 0xFFFF0000u);
}
__device__ __forceinline__ void split1(float x, short& h, short& l) {
    const unsigned u = __float_as_uint(x);
    h = (short)(u >> 16);
    const float r = x - __uint_as_float(u & 0xFFFF0000u);
    l = (short)(__float_as_uint(r) >> 16);
}

// ---------------------------------------------------------------------------
// prep: c4f[i] = coords[i,1:5] packed float4
// ---------------------------------------------------------------------------
__global__ __launch_bounds__(256) void prep_kernel(const float* __restrict__ coords,
                                                   float4* __restrict__ c4f)
{
    const int i = blockIdx.x * 256 + threadIdx.x;
    if (i < NPT) {
        const long b = (long)i * 5;
        c4f[i] = make_float4(coords[b + 1], coords[b + 2], coords[b + 3], coords[b + 4]);
    }
}

// ---------------------------------------------------------------------------
// All weight pre-converts in ONE launch (segments by blockIdx)
// ---------------------------------------------------------------------------
__global__ __launch_bounds__(256) void wsplit_all(
    const float* __restrict__ w2, const float* __restrict__ w3,
    const float* __restrict__ w4, const float* __restrict__ iw2,
    const float* __restrict__ nw1, const float* __restrict__ nw2,
    short* w2h, short* w2l, short* w3h, short* w3l,
    short* w4h, short* w4l, short* i2h, short* i2l,
    short* n1h, short* n1l, short* n2h, short* n2l)
{
    const int b = blockIdx.x;
    const float* W; int K, N, Kpad, n; short *hi, *lo;
    if (b < 512)       { W = w2;  K = 256; N = 512; Kpad = 256; hi = w2h; lo = w2l; n = b; }
    else if (b < 1280) { W = w3;  K = 512; N = 768; Kpad = 512; hi = w3h; lo = w3l; n = b - 512; }
    else if (b < 2048) { W = w4;  K = 768; N = 768; Kpad = 768; hi = w4h; lo = w4l; n = b - 1280; }
    else if (b < 2304) { W = iw2; K = 256; N = 256; Kpad = 256; hi = i2h; lo = i2l; n = b - 2048; }
    else if (b < 3072) { W = nw1; K = 768; N = 768; Kpad = 768; hi = n1h; lo = n1l; n = b - 2304; }
    else               { W = nw2; K = 768; N = 768; Kpad = 768; hi = n2h; lo = n2l; n = b - 3072; }
    for (int k = threadIdx.x; k < Kpad; k += 256) {
        short h = 0, l = 0;
        if (k < K) split1(W[(long)k * N + n], h, l);
        hi[(long)n * Kpad + k] = h;
        lo[(long)n * Kpad + k] = l;
    }
}

// ---------------------------------------------------------------------------
// W45 fusion: W45ext[N=256][Kpad=800] planes + bias45 (exact: L4 has no relu)
// ---------------------------------------------------------------------------
__global__ __launch_bounds__(256) void w45_kernel(const float* __restrict__ w4,
                                                  const float* __restrict__ iw1,
                                                  const float* __restrict__ b4,
                                                  const float* __restrict__ ib1,
                                                  short* __restrict__ hi,
                                                  short* __restrict__ lo,
                                                  float* __restrict__ bias45)
{
    const int n = blockIdx.x, tid = threadIdx.x;
    __shared__ float col[772];
    for (int j = tid; j < 772; j += 256) col[j] = iw1[(long)j * 256 + n];
    __syncthreads();
    for (int k = tid; k < 800; k += 256) {
        float v = 0.f;
        if (k < 768) {
            const float* wr = &w4[(long)k * 768];
            for (int j = 0; j < 768; ++j) v += wr[j] * col[j];
        } else if (k < 772) {
            v = col[k];
        }
        short h, l; split1(v, h, l);
        hi[(long)n * 800 + k] = h;
        lo[(long)n * 800 + k] = l;
    }
    float s = 0.f;
    for (int j = tid; j < 768; j += 256) s += b4[j] * col[j];
#pragma unroll
    for (int off = 32; off; off >>= 1) s += __shfl_down(s, off);
    __shared__ float part[4];
    if ((tid & 63) == 0) part[tid >> 6] = s;
    __syncthreads();
    if (tid == 0) bias45[n] = part[0] + part[1] + part[2] + part[3] + ib1[n];
}

// ---------------------------------------------------------------------------
// L1 multi-row: 64 rows/block
// ---------------------------------------------------------------------------
__global__ __launch_bounds__(256) void l1_kernel(const float* __restrict__ f,
                                                 const float* __restrict__ w1,
                                                 const float* __restrict__ b1,
                                                 short* __restrict__ hp,
                                                 short* __restrict__ lp,
                                                 int base,
                                                 const int* __restrict__ gather)
{
    const int r0 = blockIdx.x << 6, tid = threadIdx.x;
    float wc[6];
#pragma unroll
    for (int k = 0; k < 6; ++k) wc[k] = w1[k * 256 + tid];
    const float bb = b1[tid];
    for (int i = 0; i < 64; ++i) {
        const int r = r0 + i;
        int row = gather ? gather[r] : (base + r);
        row = (row < 0) ? 0 : ((row >= NPT) ? (NPT - 1) : row);
        float acc = bb;
#pragma unroll
        for (int k = 0; k < 6; ++k) acc += f[(long)row * 6 + k] * wc[k];
        acc = fmaxf(acc, 0.f);
        short h, l; split1(acc, h, l);
        hp[(long)r * 256 + tid] = h;
        lp[(long)r * 256 + tid] = l;
    }
}

// ---------------------------------------------------------------------------
// gather_h3: G[i][0:768] = H3[knn[off+i]][0:768]
// ---------------------------------------------------------------------------
__global__ __launch_bounds__(256) void gather_h3_kernel(const short* __restrict__ H3,
                                                        const int* __restrict__ knn_idx,
                                                        int off,
                                                        short* __restrict__ G)
{
    const int i = blockIdx.x;
    const int row = knn_idx[off + i];
    const int4* src = (const int4*)(H3 + (long)row * 768);
    int4* dst = (int4*)(G + (long)i * 768);
    if (threadIdx.x < 96) dst[threadIdx.x] = src[threadIdx.x];
}

// ---------------------------------------------------------------------------
// Split-bf16 MFMA GEMM with optional fused 16-row-group max-pool (Cpool)
// and optional fused coord-fill (CoordC: writes split coords into plane cols
// 768..771 and zeros 772..799 of Cph/Cpl, stride KpadOut=800; colb==0 only).
// ---------------------------------------------------------------------------
__global__ __launch_bounds__(256) void gemm_mf(
    const short* __restrict__ Aph, const short* __restrict__ Apl,
    const float* __restrict__ Afp, int Kpad,
    const short* __restrict__ Wth, const short* __restrict__ Wtl,
    const float* __restrict__ bias,
    short* __restrict__ Cph, short* __restrict__ Cpl, int KpadOut,
    float* __restrict__ Cf, short* __restrict__ Cp768,
    float* __restrict__ Cpool,
    const float* __restrict__ CoordC, int cfBase,
    int N, int relu)
{
    __shared__ short Ah[128 * 32];
    __shared__ short Al[128 * 32];
    __shared__ short Bh[128 * 32];
    __shared__ short Bl[128 * 32];
    const int tid = threadIdx.x;
    int rowb, colb;
    {
        const int ncol = gridDim.x, nrow = gridDim.y;
        if ((nrow & 7) == 0) {
            const int id  = blockIdx.y * ncol + blockIdx.x;
            const int sgs = ncol << 3;
            const int sg = id / sgs, wi = id % sgs;
            rowb = (sg << 3) + (wi & 7);
            colb = wi >> 3;
        } else { rowb = blockIdx.y; colb = blockIdx.x; }
    }
    const int row0 = rowb << 7, col0 = colb << 7;
    const int wave = tid >> 6, lane = tid & 63;
    const int q = lane >> 4, l16 = lane & 15;
    const int l2 = lane >> 2;
    const int ks = (lane & 3) << 3;

    f32x4 acc[2][8];
#pragma unroll
    for (int mt = 0; mt < 2; ++mt)
#pragma unroll
        for (int nt = 0; nt < 8; ++nt)
            acc[mt][nt] = (f32x4){0.f, 0.f, 0.f, 0.f};

    const int nk = Kpad >> 5;
    for (int t = 0; t < nk; ++t) {
        const int k0 = t << 5;
#pragma unroll
        for (int i = 0; i < 2; ++i) {
            const int mb = (wave << 5) + (i << 4);
            const long gb = (long)(col0 + mb + l2) * Kpad + k0 + ks;
            GL16(&Wth[gb], &Bh[mb * 32]);
            GL16(&Wtl[gb], &Bl[mb * 32]);
        }
        if (Aph) {
#pragma unroll
            for (int i = 0; i < 2; ++i) {
                const int mb = (wave << 5) + (i << 4);
                const long ga = (long)(row0 + mb + l2) * Kpad + k0 + ks;
                GL16(&Aph[ga], &Ah[mb * 32]);
                if (Apl) GL16(&Apl[ga], &Al[mb * 32]);
            }
        } else {
#pragma unroll
            for (int s = 0; s < 4; ++s) {
                const int l  = (s << 8) + tid;
                const int m  = l >> 3;
                const int k4 = (l & 7) << 2;
                const float4 v = *(const float4*)&Afp[(long)(row0 + m) * Kpad + k0 + k4];
                const unsigned u0 = __float_as_uint(v.x), u1 = __float_as_uint(v.y);
                const unsigned u2 = __float_as_uint(v.z), u3 = __float_as_uint(v.w);
                const unsigned r0 = __float_as_uint(v.x - __uint_as_float(u0 & 0xFFFF0000u));
                const unsigned r1 = __float_as_uint(v.y - __uint_as_float(u1 & 0xFFFF0000u));
                const unsigned r2 = __float_as_uint(v.z - __uint_as_float(u2 & 0xFFFF0000u));
                const unsigned r3 = __float_as_uint(v.w - __uint_as_float(u3 & 0xFFFF0000u));
                *(int2*)&Ah[m * 32 + k4] = make_int2((int)pack_hi(u0, u1), (int)pack_hi(u2, u3));
                *(int2*)&Al[m * 32 + k4] = make_int2((int)pack_hi(r0, r1), (int)pack_hi(r2, r3));
            }
        }
        __syncthreads();
        const bool useAl = (Apl != nullptr) || (Aph == nullptr);
        bf16x8 ah[2], al[2];
#pragma unroll
        for (int mt = 0; mt < 2; ++mt) {
            const int mrow = (wave << 5) + (mt << 4) + l16;
            ah[mt] = *(const bf16x8*)&Ah[mrow * 32 + (q << 3)];
            if (useAl) al[mt] = *(const bf16x8*)&Al[mrow * 32 + (q << 3)];
        }
#pragma unroll
        for (int nt = 0; nt < 8; ++nt) {
            const int ncol2 = (nt << 4) + l16;
            const bf16x8 bh = *(const bf16x8*)&Bh[ncol2 * 32 + (q << 3)];
            const bf16x8 bl = *(const bf16x8*)&Bl[ncol2 * 32 + (q << 3)];
#pragma unroll
            for (int mt = 0; mt < 2; ++mt) {
                acc[mt][nt] = __builtin_amdgcn_mfma_f32_16x16x32_bf16(ah[mt], bh, acc[mt][nt], 0, 0, 0);
                acc[mt][nt] = __builtin_amdgcn_mfma_f32_16x16x32_bf16(ah[mt], bl, acc[mt][nt], 0, 0, 0);
                if (useAl)
                    acc[mt][nt] = __builtin_amdgcn_mfma_f32_16x16x32_bf16(al[mt], bh, acc[mt][nt], 0, 0, 0);
            }
        }
        __syncthreads();
    }
    if (Cpool) {
#pragma unroll
        for (int mt = 0; mt < 2; ++mt)
#pragma unroll
            for (int nt = 0; nt < 8; ++nt) {
                const int col = col0 + (nt << 4) + l16;
                float m = fmaxf(fmaxf(acc[mt][nt][0], acc[mt][nt][1]),
                                fmaxf(acc[mt][nt][2], acc[mt][nt][3]));
                m = fmaxf(m, __shfl_xor(m, 16));
                m = fmaxf(m, __shfl_xor(m, 32));
                m += bias[col];
                if (relu) m = fmaxf(m, 0.f);
                if (q == 0)
                    Cpool[(long)((row0 >> 4) + (wave << 1) + mt) * 768 + col] = m;
            }
        return;
    }
#pragma unroll
    for (int mt = 0; mt < 2; ++mt)
#pragma unroll
        for (int nt = 0; nt < 8; ++nt) {
            const int col = col0 + (nt << 4) + l16;
            const float bs = bias[col];
#pragma unroll
            for (int rg = 0; rg < 4; ++rg) {
                const int row = row0 + (wave << 5) + (mt << 4) + (q << 2) + rg;
                float v = acc[mt][nt][rg] + bs;
                if (relu) v = fmaxf(v, 0.f);
                if (Cf) Cf[(long)row * N + col] = v;
                if (Cph || Cp768) {
                    short h, l; split1(v, h, l);
                    if (Cph) {
                        Cph[(long)row * KpadOut + col] = h;
                        Cpl[(long)row * KpadOut + col] = l;
                    }
                    if (Cp768) Cp768[(long)row * 768 + col] = h;
                }
            }
        }
    if (CoordC && Cph && colb == 0 && tid < 128) {
        const int r = row0 + tid;
        const long rb = (long)r * KpadOut;
        const long cb = (long)(cfBase + r) * 5;
#pragma unroll
        for (int d = 0; d < 4; ++d) {
            short h, l; split1(CoordC[cb + 1 + d], h, l);
            Cph[rb + 768 + d] = h;
            Cpl[rb + 768 + d] = l;
        }
        for (int c = 772; c < 800; ++c) { Cph[rb + c] = 0; Cpl[rb + c] = 0; }
    }
}

// ---------------------------------------------------------------------------
// LayerNorm multi-row: wave per row x 8 rows
// ---------------------------------------------------------------------------
__global__ __launch_bounds__(256) void ln_kernel(const float* __restrict__ z,
                                                 const float* __restrict__ g,
                                                 const float* __restrict__ b,
                                                 short* __restrict__ hp,
                                                 short* __restrict__ lp)
{
    const int tid = threadIdx.x, wave = tid >> 6, lane = tid & 63;
    float gv[4], bv[4];
#pragma unroll
    for (int j = 0; j < 4; ++j) { gv[j] = g[lane * 4 + j]; bv[j] = b[lane * 4 + j]; }
    for (int i = 0; i < 8; ++i) {
        const int r = (blockIdx.x << 5) + (wave << 3) + i;
        const float4 x = *(const float4*)&z[(long)r * 256 + lane * 4];
        float s = x.x + x.y + x.z + x.w;
#pragma unroll
        for (int off = 32; off; off >>= 1) s += __shfl_down(s, off);
        const float mu = __shfl(s, 0) * (1.f / 256.f);
        const float d0 = x.x - mu, d1 = x.y - mu, d2 = x.z - mu, d3 = x.w - mu;
        float s2 = d0 * d0 + d1 * d1 + d2 * d2 + d3 * d3;
#pragma unroll
        for (int off = 32; off; off >>= 1) s2 += __shfl_down(s2, off);
        const float den = sqrtf(__shfl(s2, 0) * (1.f / 256.f) + 1e-5f);
        const float v[4] = { d0 / den * gv[0] + bv[0], d1 / den * gv[1] + bv[1],
                             d2 / den * gv[2] + bv[2], d3 / den * gv[3] + bv[3] };
#pragma unroll
        for (int j = 0; j < 4; ++j) {
            short h, l; split1(v[j], h, l);
            hp[(long)r * 256 + lane * 4 + j] = h;
            lp[(long)r * 256 + lane * 4 + j] = l;
        }
    }
}

// ---------------------------------------------------------------------------
// imp multi-row: wave per row x 8
// ---------------------------------------------------------------------------
__global__ __launch_bounds__(256) void imp_kernel(const float* __restrict__ z2,
                                                  const float* __restrict__ iw3,
                                                  const float* __restrict__ ib3,
                                                  const float* __restrict__ noise,
                                                  const float* __restrict__ lt,
                                                  float* __restrict__ pert,
                                                  int base)
{
    const int tid = threadIdx.x, wave = tid >> 6, lane = tid & 63;
    float wv[4];
#pragma unroll
    for (int j = 0; j < 4; ++j) wv[j] = iw3[lane * 4 + j];
    const float temp = fmaxf(expf(lt[0]), 0.1f);
    const float b3v = ib3[0];
    for (int i = 0; i < 8; ++i) {
        const int r = (blockIdx.x << 5) + (wave << 3) + i;
        const float4 x = *(const float4*)&z2[(long)r * 256 + lane * 4];
        float s = x.x * wv[0] + x.y * wv[1] + x.z * wv[2] + x.w * wv[3];
#pragma unroll
        for (int off = 32; off; off >>= 1) s += __shfl_down(s, off);
        if (lane == 0)
            pert[base + r] = (s + b3v + noise[base + r]) / temp;
    }
}

// ---------------------------------------------------------------------------
// top-128 per event: 2-level cached radix; x4-replicated histograms
// (bin b at (b<<2)|(tid&3): 16-way same-address serialization instead of 64).
// ---------------------------------------------------------------------------
__device__ __forceinline__ unsigned fmap(float f) {
    unsigned x = __float_as_uint(f);
    return (x & 0x80000000u) ? ~x : (x | 0x80000000u);
}

__global__ __launch_bounds__(256) void topk_kernel(const float* __restrict__ pert,
                                                   const float4* __restrict__ c4f,
                                                   float* __restrict__ centf)
{
    const int e = blockIdx.x, tid = threadIdx.x;
    const int base = e * PPE;
    const int c4 = tid & 3;
    __shared__ unsigned short d16[PPE];          // 32 KB
    __shared__ unsigned long long ubuf[664];     // 5.2 KB phase-shared scratch
    __shared__ int sh_need; __shared__ unsigned sh_b;
    __shared__ int cgt, ceq;
    unsigned* hist4 = (unsigned*)ubuf;           // 1024
    unsigned* histm = hist4 + 1024;              // 256
    for (int i = tid; i < 1024; i += 256) hist4[i] = 0;
    __syncthreads();
    for (int p = tid; p < PPE; p += 256) {
        const unsigned u = fmap(pert[base + p]);
        d16[p] = (unsigned short)(u >> 16);
        atomicAdd(&hist4[((u >> 24) << 2) | c4], 1u);
    }
    __syncthreads();
    histm[tid] = hist4[tid << 2] + hist4[(tid << 2) | 1]
               + hist4[(tid << 2) | 2] + hist4[(tid << 2) | 3];
    __syncthreads();
    if (tid == 0) {
        int cum = 0, b = 255;
        for (; b > 0; --b) { cum += (int)histm[b]; if (cum >= MT) break; }
        if (cum < MT) { cum += (int)histm[0]; b = 0; }
        sh_need = MT - (cum - (int)histm[b]); sh_b = (unsigned)b;
    }
    __syncthreads();
    int need = sh_need;
    const unsigned b1v = sh_b;
    __syncthreads();
    for (int i = tid; i < 1024; i += 256) hist4[i] = 0;
    __syncthreads();
    for (int p = tid; p < PPE; p += 256) {
        const unsigned h = d16[p];
        if ((h >> 8) == b1v) atomicAdd(&hist4[((h & 255u) << 2) | c4], 1u);
    }
    __syncthreads();
    histm[tid] = hist4[tid << 2] + hist4[(tid << 2) | 1]
               + hist4[(tid << 2) | 2] + hist4[(tid << 2) | 3];
    __syncthreads();
    if (tid == 0) {
        int cum = 0, b = 255;
        for (; b > 0; --b) { cum += (int)histm[b]; if (cum >= need) break; }
        if (cum < need) { cum += (int)histm[0]; b = 0; }
        sh_need = need - (cum - (int)histm[b]); sh_b = (unsigned)b;
    }
    __syncthreads();
    need = sh_need;
    const unsigned prefix16 = (b1v << 8) | sh_b;
    // ---- collect phase: re-carve ubuf
    int* gt_i = (int*)ubuf;                                   // 128
    unsigned* gt_u = (unsigned*)(gt_i + MT);                  // 128
    int* eqbuf = (int*)(gt_u + MT);                           // 256
    unsigned long long* key256 = (unsigned long long*)(eqbuf + 256);  // 256
    unsigned long long* key = key256 + 256;                   // 128
    if (tid == 0) { cgt = 0; ceq = 0; }
    __syncthreads();
    for (int p = tid; p < PPE; p += 256) {
        const unsigned h = d16[p];
        if (h > prefix16)        { int q = atomicAdd(&cgt, 1); if (q < MT)  gt_i[q] = p; }
        else if (h == prefix16)  { int q = atomicAdd(&ceq, 1); if (q < 256) eqbuf[q] = p; }
    }
    __syncthreads();
    const int ngt = (cgt < MT) ? cgt : MT;
    if (tid < ngt) gt_u[tid] = fmap(pert[base + gt_i[tid]]);
    if (ceq <= 256) {
        key256[tid] = (tid < ceq)
            ? (((unsigned long long)fmap(pert[base + eqbuf[tid]]) << 32) | (unsigned)(~eqbuf[tid]))
            : 0ull;
        __syncthreads();
        for (int k = 2; k <= 256; k <<= 1)
            for (int j = k >> 1; j > 0; j >>= 1) {
                const int l = tid ^ j;
                if (l > tid) {
                    const unsigned long long a = key256[tid], b = key256[l];
                    const bool up = ((tid & k) == 0);
                    if (up ? (a < b) : (a > b)) { key256[tid] = b; key256[l] = a; }
                }
                __syncthreads();
            }
    } else if (tid == 0) {
        unsigned long long sel[MT];
        int n = 0;
        for (int p = 0; p < PPE; ++p) {
            if (d16[p] != (unsigned short)prefix16) continue;
            const unsigned long long kk =
                ((unsigned long long)fmap(pert[base + p]) << 32) | (unsigned)(~p);
            if (n < need) {
                int j = n++;
                while (j > 0 && sel[j - 1] < kk) { sel[j] = sel[j - 1]; --j; }
                sel[j] = kk;
            } else if (kk > sel[need - 1]) {
                int j = need - 1;
                while (j > 0 && sel[j - 1] < kk) { sel[j] = sel[j - 1]; --j; }
                sel[j] = kk;
            }
        }
        for (int j = 0; j < need; ++j) key256[j] = sel[j];
    }
    __syncthreads();
    if (tid < MT) {
        if (tid < ngt)
            key[tid] = ((unsigned long long)gt_u[tid] << 32) | (unsigned)(~gt_i[tid]);
        else if (tid < ngt + need)
            key[tid] = key256[tid - ngt];
        else
            key[tid] = 0ull;
    }
    __syncthreads();
    for (int k = 2; k <= MT; k <<= 1)
        for (int j = k >> 1; j > 0; j >>= 1) {
            if (tid < MT) {
                const int l = tid ^ j;
                if (l > tid) {
                    const unsigned long long a = key[tid], b = key[l];
                    const bool up = ((tid & k) == 0);
                    if (up ? (a < b) : (a > b)) { key[tid] = b; key[l] = a; }
                }
            }
            __syncthreads();
        }
    if (tid < MT) {
        const int idx = (int)(~(unsigned)(key[tid] & 0xFFFFFFFFu));
        *(float4*)&centf[(long)(e * MT + tid) * 4] = c4f[base + idx];
    }
}

// ---------------------------------------------------------------------------
// 16-NN per (event,centroid): 2-level cached radix, x4-replicated histograms
// ---------------------------------------------------------------------------
__device__ __forceinline__ unsigned d2bits(const float4 x, float c0, float c1,
                                           float c2, float c3) {
    const float q0 = __fmul_rn(c0 - x.x, c0 - x.x);
    const float q1 = __fmul_rn(c1 - x.y, c1 - x.y);
    const float q2 = __fmul_rn(c2 - x.z, c2 - x.z);
    const float q3 = __fmul_rn(c3 - x.w, c3 - x.w);
    return __float_as_uint(__fadd_rn(__fadd_rn(__fadd_rn(q0, q1), q2), q3));
}

__global__ __launch_bounds__(256) void knn_kernel(const float4* __restrict__ c4f,
                                                  const float* __restrict__ centf,
                                                  int* __restrict__ knn_idx)
{
    const int blk = blockIdx.x, tid = threadIdx.x;
    const int e = blk >> 7, base = e * PPE;
    const int c4 = tid & 3;
    const float c0 = centf[(long)blk * 4 + 0];
    const float c1 = centf[(long)blk * 4 + 1];
    const float c2 = centf[(long)blk * 4 + 2];
    const float c3 = centf[(long)blk * 4 + 3];
    __shared__ unsigned short d16[PPE];          // 32 KB
    __shared__ unsigned long long ubuf[664];
    __shared__ int sh_need; __shared__ unsigned sh_b;
    __shared__ int clt, ceq;
    unsigned* hist4 = (unsigned*)ubuf;           // 1024
    unsigned* histm = hist4 + 1024;              // 256
    for (int i = tid; i < 1024; i += 256) hist4[i] = 0;
    __syncthreads();
    for (int p = tid; p < PPE; p += 256) {
        const unsigned u = d2bits(c4f[base + p], c0, c1, c2, c3);
        d16[p] = (unsigned short)(u >> 16);
        atomicAdd(&hist4[((u >> 24) << 2) | c4], 1u);
    }
    __syncthreads();
    histm[tid] = hist4[tid << 2] + hist4[(tid << 2) | 1]
               + hist4[(tid << 2) | 2] + hist4[(tid << 2) | 3];
    __syncthreads();
    if (tid == 0) {
        int cum = 0, b = 0;
        for (; b < 255; ++b) { cum += (int)histm[b]; if (cum >= KNN) break; }
        if (cum < KNN) { cum += (int)histm[255]; b = 255; }
        sh_need = KNN - (cum - (int)histm[b]); sh_b = (unsigned)b;
    }
    __syncthreads();
    int need = sh_need;
    const unsigned b1v = sh_b;
    __syncthreads();
    for (int i = tid; i < 1024; i += 256) hist4[i] = 0;
    __syncthreads();
    for (int p = tid; p < PPE; p += 256) {
        const unsigned h = d16[p];
        if ((h >> 8) == b1v) atomicAdd(&hist4[((h & 255u) << 2) | c4], 1u);
    }
    __syncthreads();
    histm[tid] = hist4[tid << 2] + hist4[(tid << 2) | 1]
               + hist4[(tid << 2) | 2] + hist4[(tid << 2) | 3];
    __syncthreads();
    if (tid == 0) {
        int cum = 0, b = 0;
        for (; b < 255; ++b) { cum += (int)histm[b]; if (cum >= need) break; }
        if (cum < need) { cum += (int)histm[255]; b = 255; }
        sh_need = need - (cum - (int)histm[b]); sh_b = (unsigned)b;
    }
    __syncthreads();
    need = sh_need;
    const unsigned prefix16 = (b1v << 8) | sh_b;
    // ---- collect phase: re-carve ubuf
    int* lt_i = (int*)ubuf;                                   // 16
    unsigned* lt_u = (unsigned*)(lt_i + KNN);                 // 16
    int* eqbuf = (int*)(lt_u + KNN);                          // 256
    unsigned long long* key256 = (unsigned long long*)(eqbuf + 256);  // 256
    if (tid == 0) { clt = 0; ceq = 0; }
    __syncthreads();
    for (int p = tid; p < PPE; p += 256) {
        const unsigned h = d16[p];
        if (h < prefix16)        { int q = atomicAdd(&clt, 1); if (q < KNN) lt_i[q] = p; }
        else if (h == prefix16)  { int q = atomicAdd(&ceq, 1); if (q < 256) eqbuf[q] = p; }
    }
    __syncthreads();
    const int nlt = (clt < KNN) ? clt : KNN;
    if (tid < nlt) lt_u[tid] = d2bits(c4f[base + lt_i[tid]], c0, c1, c2, c3);
    if (ceq <= 256) {
        key256[tid] = (tid < ceq)
            ? (((unsigned long long)d2bits(c4f[base + eqbuf[tid]], c0, c1, c2, c3) << 32)
               | (unsigned)eqbuf[tid])
            : 0xFFFFFFFFFFFFFFFFull;
        __syncthreads();
        for (int k = 2; k <= 256; k <<= 1)
            for (int j = k >> 1; j > 0; j >>= 1) {
                const int l = tid ^ j;
                if (l > tid) {
                    const unsigned long long a = key256[tid], b = key256[l];
                    const bool up = ((tid & k) == 0);
                    if (up ? (a > b) : (a < b)) { key256[tid] = b; key256[l] = a; }
                }
                __syncthreads();
            }
    } else if (tid == 0) {
        unsigned long long sel[KNN];
        int n = 0;
        for (int p = 0; p < PPE; ++p) {
            if (d16[p] != (unsigned short)prefix16) continue;
            const unsigned long long kk =
                ((unsigned long long)d2bits(c4f[base + p], c0, c1, c2, c3) << 32) | (unsigned)p;
            if (n < need) {
                int j = n++;
                while (j > 0 && sel[j - 1] > kk) { sel[j] = sel[j - 1]; --j; }
                sel[j] = kk;
            } else if (kk < sel[need - 1]) {
                int j = need - 1;
                while (j > 0 && sel[j - 1] > kk) { sel[j] = sel[j - 1]; --j; }
                sel[j] = kk;
            }
        }
        for (int j = 0; j < need; ++j) key256[j] = sel[j];
    }
    __syncthreads();
    if (tid == 0) {
        unsigned long long fin[KNN];
        int n = 0;
        for (int i = 0; i < nlt; ++i) {
            const unsigned long long kk = ((unsigned long long)lt_u[i] << 32) | (unsigned)lt_i[i];
            int j = n++;
            while (j > 0 && fin[j - 1] > kk) { fin[j] = fin[j - 1]; --j; }
            fin[j] = kk;
        }
        for (int i = 0; i < need; ++i) {
            const unsigned long long kk = key256[i];
            int j = n++;
            while (j > 0 && fin[j - 1] > kk) { fin[j] = fin[j - 1]; --j; }
            fin[j] = kk;
        }
        for (int r = 0; r < KNN; ++r)
            knn_idx[blk * KNN + r] = base + (int)(unsigned)(fin[r] & 0xFFFFFFFFu);
    }
}

// ---------------------------------------------------------------------------
// emit parallel: grid (BATCH, 16)
// ---------------------------------------------------------------------------
__global__ __launch_bounds__(256) void emit_kernel(const float* __restrict__ centf,
                                                   const float* __restrict__ tokf,
                                                   float* __restrict__ out,
                                                   long out_size)
{
    const int e = blockIdx.x, s = blockIdx.y, tid = threadIdx.x;
    __shared__ float tv[MT];
    __shared__ int   rk[MT];
    if (tid < MT) tv[tid] = centf[(long)(e * MT + tid) * 4 + 3];
    __syncthreads();
    if (tid < MT) {
        const float t = tv[tid]; int r = 0;
        for (int j = 0; j < MT; ++j)
            r += (tv[j] < t || (tv[j] == t && j < tid)) ? 1 : 0;
        rk[tid] = r;
    }
    __syncthreads();
    const long cent_off = (long)BATCH * MT * TOKD;
    const long mask_off = cent_off + (long)BATCH * MT * 4;
    for (int i = s * 8; i < s * 8 + 8; ++i) {
        const float* src = tokf + ((size_t)e * MT + i) * TOKD;
        const long dst = ((long)e * MT + rk[i]) * TOKD;
        for (int t4 = tid; t4 < TOKD / 4; t4 += 256) {
            const float4 v = ((const float4*)src)[t4];
            const long g = dst + (long)t4 * 4;
            if (g + 3 < out_size) {
                *(float4*)&out[g] = v;
            } else {
                if (g + 0 < out_size) out[g + 0] = v.x;
                if (g + 1 < out_size) out[g + 1] = v.y;
                if (g + 2 < out_size) out[g + 2] = v.z;
                if (g + 3 < out_size) out[g + 3] = v.w;
            }
        }
    }
    if (s == 0) {
        for (int idx = tid; idx < MT * 4; idx += 256) {
            const int i = idx >> 2, d = idx & 3;
            const long g = cent_off + ((long)e * MT + rk[i]) * 4 + d;
            if (g < out_size) out[g] = centf[((long)e * MT + i) * 4 + d];
        }
        for (int idx = tid; idx < MT; idx += 256) {
            const long g = mask_off + (long)e * MT + idx;
            if (g < out_size) out[g] = 1.0f;
        }
    }
}

// ---------------------------------------------------------------------------
extern "C" void kernel_launch(void* const* d_in, const int* in_sizes, int n_in,
                              void* d_out, int out_size, void* d_ws, size_t ws_size,
                              hipStream_t stream)
{
    const float* coords = (const float*)d_in[0];
    const float* feats  = (const float*)d_in[1];
    const float* lt     = (const float*)d_in[2];
    const float* w1  = (const float*)d_in[3];  const float* b1  = (const float*)d_in[4];
    const float* w2  = (const float*)d_in[5];  const float* b2  = (const float*)d_in[6];
    const float* w3  = (const float*)d_in[7];  const float* b3  = (const float*)d_in[8];
    const float* w4  = (const float*)d_in[9];  const float* b4  = (const float*)d_in[10];
    const float* iw1 = (const float*)d_in[11]; const float* ib1 = (const float*)d_in[12];
    const float* lng = (const float*)d_in[13]; const float* lnb = (const float*)d_in[14];
    const float* iw2 = (const float*)d_in[15]; const float* ib2 = (const float*)d_in[16];
    const float* iw3 = (const float*)d_in[17]; const float* ib3 = (const float*)d_in[18];
    const float* nw1 = (const float*)d_in[19]; const float* nb1 = (const float*)d_in[20];
    const float* nw2 = (const float*)d_in[21]; const float* nb2 = (const float*)d_in[22];
    const float* noise = (const float*)d_in[23];

    const int NBR = BATCH * MT * KNN;   // 16384
    const size_t FIXED_FL = (size_t)NPT + 4096 + 16384 + (size_t)1024 * TOKD
                          + (size_t)NPT * 4 + 256 + 2 * (size_t)1024 * TOKD;
    const size_t s_w2 = 512 * 256,  s_w3 = 768 * 512,  s_w4 = 768 * 768;
    const size_t s_45 = 256 * 800,  s_i2 = 256 * 256;
    const size_t s_n1 = 768 * 768,  s_n2 = 768 * 768;
    const size_t WTOT = 2 * (s_w2 + s_w3 + s_w4 + s_45 + s_i2 + s_n1 + s_n2);
    const size_t BASE_BYTES = FIXED_FL * 4 + WTOT * 2;
    const size_t PERROW = 8448;
    int ch = 128;
    while (ch < NPT && BASE_BYTES + (size_t)(ch * 2) * PERROW <= ws_size) ch <<= 1;
    const size_t H3_BYTES = (size_t)NPT * 768 * 2;
    const bool persist = (BASE_BYTES + (size_t)ch * PERROW + H3_BYTES) <= ws_size;

    float*  pert   = (float*)d_ws;
    float*  centf  = pert + NPT;
    int*    knn    = (int*)(centf + 4096);
    float*  pooled = (float*)(knn + 16384);
    float4* c4f    = (float4*)(pooled + (size_t)1024 * TOKD);
    float*  bias45 = (float*)(c4f + NPT);
    float*  T1     = bias45 + 256;                      // 1024*768
    float*  T2     = T1 + (size_t)1024 * TOKD;          // 1024*768
    short*  wsp    = (short*)(T2 + (size_t)1024 * TOKD);
    short* w2h = wsp;            short* w2l = w2h + s_w2;
    short* w3h = w2l + s_w2;     short* w3l = w3h + s_w3;
    short* w4h = w3l + s_w3;     short* w4l = w4h + s_w4;
    short* f45h = w4l + s_w4;    short* f45l = f45h + s_45;
    short* i2h = f45l + s_45;    short* i2l = i2h + s_i2;
    short* n1h = i2l + s_i2;     short* n1l = n1h + s_n1;
    short* n2h = n1l + s_n1;     short* n2l = n2h + s_n2;
    short* PAh = n2l + s_n2;     short* PAl = PAh + (size_t)ch * 800;
    short* PBh = PAl + (size_t)ch * 800;
    short* PBl = PBh + (size_t)ch * 800;
    float* F2  = (float*)(PBl + (size_t)ch * 800);      // ch*256 fp32 (z1)
    float* F1z = F2 + (size_t)ch * 256;                 // ch*256 fp32 (z2)
    short* H3  = (short*)(F1z + (size_t)ch * 256);      // NPT*768 bf16-hi (opt)

    prep_kernel<<<dim3((NPT + 255) / 256), dim3(256), 0, stream>>>(coords, c4f);
    wsplit_all<<<dim3(3840), dim3(256), 0, stream>>>(
        w2, w3, w4, iw2, nw1, nw2,
        w2h, w2l, w3h, w3l, w4h, w4l, i2h, i2l, n1h, n1l, n2h, n2l);
    w45_kernel<<<dim3(256), dim3(256), 0, stream>>>(w4, iw1, b4, ib1, f45h, f45l, bias45);

    for (int ck = 0; ck < NPT / ch; ++ck) {
        const int base = ck * ch;
        l1_kernel<<<dim3(ch / 64), dim3(256), 0, stream>>>(feats, w1, b1, PAh, PAl, base, nullptr);
        gemm_mf<<<dim3(512 / 128, ch / 128), dim3(256), 0, stream>>>(
            PAh, PAl, nullptr, 256, w2h, w2l, b2, PBh, PBl, 512,
            nullptr, nullptr, nullptr, nullptr, 0, 512, 1);
        gemm_mf<<<dim3(768 / 128, ch / 128), dim3(256), 0, stream>>>(
            PBh, PBl, nullptr, 512, w3h, w3l, b3, PAh, PAl, 800,
            nullptr, persist ? (H3 + (size_t)base * 768) : nullptr, nullptr,
            coords, base, 768, 1);
        gemm_mf<<<dim3(256 / 128, ch / 128), dim3(256), 0, stream>>>(
            PAh, PAl, nullptr, 800, f45h, f45l, bias45, nullptr, nullptr, 0,
            F2, nullptr, nullptr, nullptr, 0, 256, 1);
        ln_kernel<<<dim3(ch / 32), dim3(256), 0, stream>>>(F2, lng, lnb, PBh, PBl);
        gemm_mf<<<dim3(256 / 128, ch / 128), dim3(256), 0, stream>>>(
            PBh, PBl, nullptr, 256, i2h, i2l, ib2, nullptr, nullptr, 0,
            F1z, nullptr, nullptr, nullptr, 0, 256, 1);
        imp_kernel<<<dim3(ch / 32), dim3(256), 0, stream>>>(F1z, iw3, ib3, noise, lt, pert, base);
    }

    topk_kernel<<<dim3(BATCH), dim3(256), 0, stream>>>(pert, c4f, centf);
    knn_kernel<<<dim3(BATCH * MT), dim3(256), 0, stream>>>(c4f, centf, knn);

    const int rcch = (ch < NBR) ? ch : NBR;
    for (int rc = 0; rc < NBR / rcch; ++rc) {
        if (persist) {
            gather_h3_kernel<<<dim3(rcch), dim3(256), 0, stream>>>(
                H3, knn, rc * rcch, PAh);
            gemm_mf<<<dim3(768 / 128, rcch / 128), dim3(256), 0, stream>>>(
                PAh, nullptr, nullptr, 768, w4h, w4l, b4, nullptr, nullptr, 0,
                nullptr, nullptr, pooled + (size_t)(rc * rcch / 16) * 768,
                nullptr, 0, 768, 0);
        } else {
            l1_kernel<<<dim3(rcch / 64), dim3(256), 0, stream>>>(feats, w1, b1, PAh, PAl, 0, knn + (size_t)rc * rcch);
            gemm_mf<<<dim3(512 / 128, rcch / 128), dim3(256), 0, stream>>>(
                PAh, PAl, nullptr, 256, w2h, w2l, b2, PBh, PBl, 512,
                nullptr, nullptr, nullptr, nullptr, 0, 512, 1);
            gemm_mf<<<dim3(768 / 128, rcch / 128), dim3(256), 0, stream>>>(
                PBh, PBl, nullptr, 512, w3h, w3l, b3, PAh, PAl, 768,
                nullptr, nullptr, nullptr, nullptr, 0, 768, 1);
            gemm_mf<<<dim3(768 / 128, rcch / 128), dim3(256), 0, stream>>>(
                PAh, PAl, nullptr, 768, w4h, w4l, b4, nullptr, nullptr, 0,
                nullptr, nullptr, pooled + (size_t)(rc * rcch / 16) * 768,
                nullptr, 0, 768, 0);
        }
    }

    // ---- token MLP (1024x768, fp32-A) + parallel emit ----
    gemm_mf<<<dim3(768 / 128, 1024 / 128), dim3(256), 0, stream>>>(
        nullptr, nullptr, pooled, 768, n1h, n1l, nb1, nullptr, nullptr, 0,
        T1, nullptr, nullptr, nullptr, 0, 768, 1);
    gemm_mf<<<dim3(768 / 128, 1024 / 128), dim3(256), 0, stream>>>(
        nullptr, nullptr, T1, 768, n2h, n2l, nb2, nullptr, nullptr, 0,
        T2, nullptr, nullptr, nullptr, 0, 768, 0);
    emit_kernel<<<dim3(BATCH, 16), dim3(256), 0, stream>>>(
        centf, T2, (float*)d_out, (long)out_size);
}